// Round 8
// baseline (596.016 us; speedup 1.0000x reference)
//
#include <hip/hip_runtime.h>
#include <math.h>

#define B_ 2
#define S_ 2048
#define H_ 16
#define DH_ 64
#define D_ 1024
#define MEM_ 1000
#define KT_ 10
#define THRESH_ 0.5
#define BS_ (B_ * S_)
#define EVCAP_ (2 * S_)   // max possible events (<= S per sample)

typedef float f32x4 __attribute__((ext_vector_type(4)));
typedef short bf16x8 __attribute__((ext_vector_type(8)));
typedef short s16x4 __attribute__((ext_vector_type(4)));

__device__ inline unsigned short f2bf(float f) {
    union { float f; unsigned u; } v; v.f = f;
    unsigned u = v.u;
    unsigned r = (u + 0x7FFFu + ((u >> 16) & 1u)) >> 16;  // RNE
    return (unsigned short)r;
}
__device__ inline float bf2f(unsigned short h) {
    union { unsigned u; float f; } v; v.u = ((unsigned)h) << 16; return v.f;
}

// async global->LDS, 16B per lane; LDS dest = wave-uniform base + lane*16
__device__ __forceinline__ void gload16(const short* gp, const short* lp) {
    __builtin_amdgcn_global_load_lds(
        (__attribute__((address_space(1))) void*)(unsigned long long)gp,
        (__attribute__((address_space(3))) void*)(unsigned)(unsigned long long)lp,
        16, 0, 0);
}

// ---------------- init ----------------
__global__ void init_counters(int* scal) { scal[0] = 0; scal[1] = 0; scal[2] = 0; }

// ---------------- split f32 -> bf16 chunks (h, m, optional l) ----------------
template <bool WL>
__global__ __launch_bounds__(256) void split_f32_kernel(const float* __restrict__ src,
                                                        short* __restrict__ h,
                                                        short* __restrict__ m,
                                                        short* __restrict__ l,
                                                        int n4)
{
    int i = blockIdx.x * 256 + threadIdx.x;
    if (i >= n4) return;
    float4 x = ((const float4*)src)[i];
    float xs[4] = {x.x, x.y, x.z, x.w};
    s16x4 hv, mv, lv;
#pragma unroll
    for (int j = 0; j < 4; ++j) {
        unsigned short hb = f2bf(xs[j]);
        float hf = bf2f(hb);
        float r1 = xs[j] - hf;            // exact in f32
        unsigned short mb = f2bf(r1);
        hv[j] = (short)hb; mv[j] = (short)mb;
        if (WL) {
            float mf = bf2f(mb);
            lv[j] = (short)f2bf(r1 - mf); // exact residual, rounded
        }
    }
    ((s16x4*)h)[i] = hv;
    ((s16x4*)m)[i] = mv;
    if (WL) ((s16x4*)l)[i] = lv;
}

// ---------------- multi-job 128x128 split-precision bf16 MFMA GEMM -----------
struct FArgs {
    const short* A[4][3];   // per-group A term pointers (term id = gs>>4)
    const short* B[4][3];
    short* outb[4];         // bf16 output (or null)
    float* outf[4];         // f32 output (used when outb[g]==null)
    int gsbase[4];          // global K-step base per group
    int nsteps;             // K-steps per block
    int jshift;             // log2(ngroups*8)
};

__global__ __launch_bounds__(256) void gemm_ms(FArgs fa)
{
    __shared__ __align__(16) short As[128 * 64];
    __shared__ __align__(16) short Bs[128 * 64];
    int wg = blockIdx.x;
    int q = gridDim.x >> 3;
    int lin = (wg & 7) * q + (wg >> 3);      // XCD-clustered linear id
    int by = lin >> fa.jshift;               // row panel 0..31
    int jb = lin & ((1 << fa.jshift) - 1);
    int g = jb >> 3;                         // job group
    int bcol = jb & 7;                       // col panel 0..7

    int tid = threadIdx.x;
    int w = tid >> 6, l = tid & 63;
    int wr = w >> 1, wc = w & 1;
    int lg = l >> 4, lc = l & 15;
    int jr = l >> 3;        // row within 8-row chunk
    int jc = l & 7;         // 16B col unit (8 shorts)
    int gs0 = fa.gsbase[g];

    f32x4 acc[4][4] = {};

    for (int s = 0; s < fa.nsteps; ++s) {
        int gs = gs0 + s;
        int t = gs >> 4;
        int k0 = (gs & 15) << 6;
        const short* Abase = fa.A[g][t] + (size_t)(by * 128) * D_ + k0 + jc * 8;
        const short* Bbase = fa.B[g][t] + (size_t)(bcol * 128) * D_ + k0 + jc * 8;
        __syncthreads();    // previous compute done reading LDS
#pragma unroll
        for (int i = 0; i < 4; ++i) {
            int chunk = w * 4 + i;
            int row = chunk * 8 + jr;
            gload16(Abase + (size_t)row * D_, As + chunk * 512);
            gload16(Bbase + (size_t)row * D_, Bs + chunk * 512);
        }
        __syncthreads();    // vmcnt(0) drained -> tile ready
#pragma unroll
        for (int kh = 0; kh < 2; ++kh) {
            bf16x8 av[4], bv[4];
#pragma unroll
            for (int mf = 0; mf < 4; ++mf)
                av[mf] = *(const bf16x8*)&As[(wr * 64 + mf * 16 + lc) * 64 + kh * 32 + lg * 8];
#pragma unroll
            for (int nf = 0; nf < 4; ++nf)
                bv[nf] = *(const bf16x8*)&Bs[(wc * 64 + nf * 16 + lc) * 64 + kh * 32 + lg * 8];
#pragma unroll
            for (int mf = 0; mf < 4; ++mf)
#pragma unroll
                for (int nf = 0; nf < 4; ++nf)
                    acc[mf][nf] = __builtin_amdgcn_mfma_f32_16x16x32_bf16(av[mf], bv[nf], acc[mf][nf], 0, 0, 0);
        }
    }

    if (fa.outb[g]) {
        short* ob = fa.outb[g];
#pragma unroll
        for (int mf = 0; mf < 4; ++mf)
#pragma unroll
            for (int nf = 0; nf < 4; ++nf)
#pragma unroll
                for (int reg = 0; reg < 4; ++reg) {
                    int row = by * 128 + wr * 64 + mf * 16 + lg * 4 + reg;
                    int col = bcol * 128 + wc * 64 + nf * 16 + lc;
                    ob[(size_t)row * D_ + col] = (short)f2bf(acc[mf][nf][reg]);
                }
    } else {
        float* of = fa.outf[g];
#pragma unroll
        for (int mf = 0; mf < 4; ++mf)
#pragma unroll
            for (int nf = 0; nf < 4; ++nf)
#pragma unroll
                for (int reg = 0; reg < 4; ++reg) {
                    int row = by * 128 + wr * 64 + mf * 16 + lg * 4 + reg;
                    int col = bcol * 128 + wc * 64 + nf * 16 + lc;
                    of[(size_t)row * D_ + col] = acc[mf][nf][reg];
                }
    }
}

// ---------------- V transpose: vbf[token][d] -> vbfT[b*H+h][d][token] ----------
__global__ __launch_bounds__(256) void transpose_v(const short* __restrict__ vbf,
                                                   short* __restrict__ vbfT)
{
    __shared__ short st[64][70];
    int s0 = blockIdx.x * 64;        // token tile within batch
    int h = blockIdx.y;              // head (d tile = h*64)
    int b = blockIdx.z;
    int tid = threadIdx.x;
    int r = tid >> 2, cb = (tid & 3) * 16;
    const short* src = vbf + (size_t)(b * S_ + s0 + r) * D_ + h * DH_ + cb;
    *(bf16x8*)&st[r][cb] = *(const bf16x8*)src;
    *(bf16x8*)&st[r][cb + 8] = *(const bf16x8*)(src + 8);
    __syncthreads();
    int c = tid >> 2, sb = (tid & 3) * 16;
    short tmp[16];
#pragma unroll
    for (int i = 0; i < 16; ++i) tmp[i] = st[sb + i][c];
    short* dst = vbfT + ((size_t)(b * H_ + h) * DH_ + c) * S_ + s0 + sb;
    *(bf16x8*)dst = *(bf16x8*)&tmp[0];
    *(bf16x8*)(dst + 8) = *(bf16x8*)&tmp[8];
}

// ---------------- split-K adds ----------------
__global__ __launch_bounds__(256) void addk_kernel(float* __restrict__ kf,
                                                   const float* __restrict__ kp1,
                                                   short* __restrict__ kbf)
{
    size_t i = (size_t)blockIdx.x * 256 + threadIdx.x;
    float4 a = ((const float4*)kf)[i];
    float4 b = ((const float4*)kp1)[i];
    float4 s = {a.x + b.x, a.y + b.y, a.z + b.z, a.w + b.w};
    ((float4*)kf)[i] = s;
    s16x4 o;
    o[0] = (short)f2bf(s.x); o[1] = (short)f2bf(s.y);
    o[2] = (short)f2bf(s.z); o[3] = (short)f2bf(s.w);
    ((s16x4*)kbf)[i] = o;
}

__global__ __launch_bounds__(256) void addo4_kernel(const float* __restrict__ p0,
                                                    const float* __restrict__ p1,
                                                    const float* __restrict__ p2,
                                                    const float* __restrict__ p3,
                                                    float* __restrict__ out)
{
    size_t i = (size_t)blockIdx.x * 256 + threadIdx.x;
    float4 a = ((const float4*)p0)[i];
    float4 b = ((const float4*)p1)[i];
    float4 c = ((const float4*)p2)[i];
    float4 d = ((const float4*)p3)[i];
    float4 s = {((a.x + b.x) + c.x) + d.x, ((a.y + b.y) + c.y) + d.y,
                ((a.z + b.z) + c.z) + d.z, ((a.w + b.w) + c.w) + d.w};
    ((float4*)out)[i] = s;
}

// ---------------- surprise (both batches): sur[b][t] = ||kf[t]-kf[t-1]|| ----------
__global__ __launch_bounds__(256) void surprise_kernel(const float* __restrict__ kf,
                                                       double* __restrict__ sur)
{
    int t = blockIdx.x;
    int b = blockIdx.y;
    if (t == 0) { if (threadIdx.x == 0) sur[(size_t)b * S_] = 0.0; return; }
    const float* kfb = kf + (size_t)b * S_ * D_;
    __shared__ double red[256];
    double acc = 0.0;
    for (int d = threadIdx.x; d < D_; d += 256) {
        double df = (double)kfb[(size_t)t * D_ + d] - (double)kfb[(size_t)(t - 1) * D_ + d];
        acc += df * df;
    }
    red[threadIdx.x] = acc;
    __syncthreads();
    for (int s = 128; s > 0; s >>= 1) {
        if (threadIdx.x < s) red[threadIdx.x] += red[threadIdx.x + s];
        __syncthreads();
    }
    if (threadIdx.x == 0) sur[(size_t)b * S_ + t] = sqrt(red[0]);
}

// ---------------- boundaries (parallel flags + prefix scan) ----------------
__global__ __launch_bounds__(256) void boundary_kernel(const double* __restrict__ sur,
                                                       int* __restrict__ seg_start,
                                                       int* __restrict__ seg_end,
                                                       int* __restrict__ scal)
{
    __shared__ double lsur[S_];
    __shared__ double red[256];
    __shared__ double sh_mean, sh_thr;
    __shared__ int cnt[256];
    int tid = threadIdx.x;
    for (int t = tid; t < S_; t += 256) lsur[t] = sur[t];
    __syncthreads();
    double a = 0.0;
    for (int t = tid; t < S_; t += 256) a += lsur[t];
    red[tid] = a;
    __syncthreads();
    for (int s = 128; s > 0; s >>= 1) {
        if (tid < s) red[tid] += red[tid + s];
        __syncthreads();
    }
    if (tid == 0) sh_mean = red[0] / (double)S_;
    __syncthreads();
    double mean = sh_mean;
    a = 0.0;
    for (int t = tid; t < S_; t += 256) { double d = lsur[t] - mean; a += d * d; }
    red[tid] = a;
    __syncthreads();
    for (int s = 128; s > 0; s >>= 1) {
        if (tid < s) red[tid] += red[tid + s];
        __syncthreads();
    }
    if (tid == 0) sh_thr = mean + THRESH_ * sqrt(red[0] / (double)(S_ - 1));
    __syncthreads();
    double thr = sh_thr;
    bool flg[8];
    int c = 0;
#pragma unroll
    for (int j = 0; j < 8; ++j) {
        int t = tid * 8 + j;
        flg[j] = (lsur[t] > thr) || (t == S_ - 1);
        c += flg[j] ? 1 : 0;
    }
    cnt[tid] = c;
    __syncthreads();
    for (int off = 1; off < 256; off <<= 1) {   // Hillis-Steele inclusive scan
        int v = cnt[tid];
        int add = (tid >= off) ? cnt[tid - off] : 0;
        __syncthreads();
        cnt[tid] = v + add;
        __syncthreads();
    }
    int r = (tid == 0) ? 0 : cnt[tid - 1];
#pragma unroll
    for (int j = 0; j < 8; ++j) {
        if (flg[j]) { seg_end[r] = tid * 8 + j; ++r; }
    }
    __syncthreads();
    int n = cnt[255];
    for (int i = tid; i < n; i += 256)
        seg_start[i] = (i == 0) ? 0 : seg_end[i - 1] + 1;
    if (tid == 0) {
        scal[1] = n;         // nseg
        scal[2] = scal[0];   // ev_base
        scal[0] += n;        // ev_count
    }
}

// ---------------- segment means -> append events ----------------
__global__ __launch_bounds__(256) void seg_means_kernel(const float* __restrict__ kfb,
                                                        float* __restrict__ events,
                                                        const int* __restrict__ seg_start,
                                                        const int* __restrict__ seg_end,
                                                        const int* __restrict__ scal)
{
    int g = blockIdx.x;
    if (g >= scal[1]) return;
    int s = seg_start[g], e = seg_end[g];
    double inv = 1.0 / (double)(e - s + 1);
    size_t obase = (size_t)(scal[2] + g) * D_;
    for (int d = threadIdx.x; d < D_; d += 256) {
        double acc = 0.0;
        for (int r = s; r <= e; ++r) acc += (double)kfb[(size_t)r * D_ + d];
        events[obase + d] = (float)(acc * inv);
    }
}

// ---------------- cosine sims of memory window vs last key ----------------
__global__ __launch_bounds__(256) void sims_kernel(const float* __restrict__ events,
                                                   const float* __restrict__ q,
                                                   float* __restrict__ sims,
                                                   const int* __restrict__ scal)
{
    int e = blockIdx.x;
    int total = scal[0];
    int w = total < MEM_ ? total : MEM_;
    if (e >= w) { if (threadIdx.x == 0) sims[e] = -INFINITY; return; }
    int wstart = total - w;
    const float* ev = events + (size_t)(wstart + e) * D_;
    __shared__ double r1[256], r2[256], r3[256];
    int tid = threadIdx.x;
    double dot = 0.0, n2 = 0.0, q2 = 0.0;
    for (int d = tid; d < D_; d += 256) {
        double ed = ev[d], qd = q[d];
        dot += ed * qd; n2 += ed * ed; q2 += qd * qd;
    }
    r1[tid] = dot; r2[tid] = n2; r3[tid] = q2;
    __syncthreads();
    for (int s = 128; s > 0; s >>= 1) {
        if (tid < s) { r1[tid] += r1[tid + s]; r2[tid] += r2[tid + s]; r3[tid] += r3[tid + s]; }
        __syncthreads();
    }
    if (tid == 0) {
        double mn = sqrt(r2[0]); if (mn < 1e-8) mn = 1e-8;
        double qn = sqrt(r3[0]); if (qn < 1e-8) qn = 1e-8;
        sims[e] = (float)(r1[0] / (mn * qn));
    }
}

// ---------------- top-KT selection + gather (tie -> lower index, like lax.top_k) ----------------
__global__ __launch_bounds__(256) void topk_kernel(const float* __restrict__ events,
                                                   float* __restrict__ sims,
                                                   float* __restrict__ retb,
                                                   const int* __restrict__ scal)
{
    int total = scal[0];
    int w = total < MEM_ ? total : MEM_;
    int wstart = total - w;
    __shared__ float bv[256];
    __shared__ int bidx[256];
    __shared__ int chosen;
    int tid = threadIdx.x;
    for (int r = 0; r < KT_; ++r) {
        float best = -INFINITY;
        int bi = 0x7fffffff;
        for (int e = tid; e < w; e += 256) {
            float v = sims[e];
            if (v > best || (v == best && e < bi)) { best = v; bi = e; }
        }
        bv[tid] = best; bidx[tid] = bi;
        __syncthreads();
        for (int s = 128; s > 0; s >>= 1) {
            if (tid < s) {
                if (bv[tid + s] > bv[tid] || (bv[tid + s] == bv[tid] && bidx[tid + s] < bidx[tid])) {
                    bv[tid] = bv[tid + s]; bidx[tid] = bidx[tid + s];
                }
            }
            __syncthreads();
        }
        if (tid == 0) {
            chosen = (r < w) ? bidx[0] : -1;
            if (chosen >= 0) sims[chosen] = -INFINITY;
        }
        __syncthreads();
        int c = chosen;
        if (c >= 0) {
            const float* ev = events + (size_t)(wstart + c) * D_;
            for (int d = tid; d < D_; d += 256) retb[(size_t)r * D_ + d] = ev[d];
        } else {
            for (int d = tid; d < D_; d += 256) retb[(size_t)r * D_ + d] = 0.0f;
        }
        __syncthreads();
    }
}

// ---------------- attention: bf16 MFMA flash, pre-transposed V, R6 structure ----
#define QTT 64
#define KTT 64
__global__ __launch_bounds__(256) void attn_mfma_kernel(const short* __restrict__ qbf,
                                                        const short* __restrict__ kbf,
                                                        const short* __restrict__ vbfT,
                                                        const float* __restrict__ ret,
                                                        const int* __restrict__ amask,
                                                        short* __restrict__ AOh,
                                                        short* __restrict__ AOm)
{
    __shared__ __align__(16) short k_s[KTT][72];
    __shared__ __align__(16) short vT_s[DH_][72];
    __shared__ __align__(16) short p_s[4][16][72];

    int qt = (gridDim.x - 1) - blockIdx.x;   // heavy (large-qt) blocks first
    int h = blockIdx.y, b = blockIdx.z;
    int q0 = qt * QTT;
    int tid = threadIdx.x;
    int w = tid >> 6, l = tid & 63;
    int lg = l >> 4, lc = l & 15;
    int qb = q0 + w * 16;
    float slope = exp2f(-0.5f * (float)(h + 1));

    bf16x8 qfr[2];
#pragma unroll
    for (int half = 0; half < 2; ++half)
        qfr[half] = *(const bf16x8*)(qbf + ((size_t)(b * S_ + qb + lc)) * D_ + h * DH_ + half * 32 + lg * 8);

    float mrow[4], lrow[4], fac[4];
#pragma unroll
    for (int r = 0; r < 4; ++r) { mrow[r] = -INFINITY; lrow[r] = 0.0f; }
    f32x4 O[4] = {};

    int sr = tid >> 2;              // staging row (K: key; V: d)
    int sc0 = (tid & 3) * 16;       // staging col base (K: d; V: key)

    int nreal = qt + 1;
    for (int tile = 0; tile <= nreal; ++tile) {
        bool memtile = (tile == nreal);
        int j0 = tile * KTT;
        __syncthreads();   // protect LDS from previous iteration's readers
        if (!memtile) {
            const short* kp = kbf + ((size_t)(b * S_ + j0 + sr)) * D_ + h * DH_ + sc0;
            *(bf16x8*)&k_s[sr][sc0] = *(const bf16x8*)kp;
            *(bf16x8*)&k_s[sr][sc0 + 8] = *(const bf16x8*)(kp + 8);
            const short* vp = vbfT + ((size_t)(b * H_ + h) * DH_ + sr) * S_ + j0 + sc0;
            *(bf16x8*)&vT_s[sr][sc0] = *(const bf16x8*)vp;
            *(bf16x8*)&vT_s[sr][sc0 + 8] = *(const bf16x8*)(vp + 8);
        } else {
            short kv[16];
            if (sr < KT_) {
                const float* rp = ret + ((size_t)(b * KT_ + sr)) * D_ + h * DH_ + sc0;
#pragma unroll
                for (int i = 0; i < 4; ++i) {
                    float4 a = *(const float4*)(rp + i * 4);
                    kv[i * 4 + 0] = (short)f2bf(a.x); kv[i * 4 + 1] = (short)f2bf(a.y);
                    kv[i * 4 + 2] = (short)f2bf(a.z); kv[i * 4 + 3] = (short)f2bf(a.w);
                }
            } else {
#pragma unroll
                for (int i = 0; i < 16; ++i) kv[i] = 0;
            }
            *(bf16x8*)&k_s[sr][sc0] = *(bf16x8*)&kv[0];
            *(bf16x8*)&k_s[sr][sc0 + 8] = *(bf16x8*)&kv[8];
            short tv[16];
#pragma unroll
            for (int i = 0; i < 16; ++i) {
                int key = sc0 + i;
                tv[i] = (key < KT_) ? (short)f2bf(ret[((size_t)(b * KT_ + key)) * D_ + h * DH_ + sr]) : (short)0;
            }
            *(bf16x8*)&vT_s[sr][sc0] = *(bf16x8*)&tv[0];
            *(bf16x8*)&vT_s[sr][sc0 + 8] = *(bf16x8*)&tv[8];
        }
        __syncthreads();

        // ---- QK^T scores (C: row = lg*4+reg = query, col = lc = key) ----
        float sc[4][4];
        int am[4];
        if (!memtile) {
#pragma unroll
            for (int kt = 0; kt < 4; ++kt) am[kt] = amask[b * S_ + j0 + kt * 16 + lc];
        }
#pragma unroll
        for (int kt = 0; kt < 4; ++kt) {
            f32x4 s = {0.0f, 0.0f, 0.0f, 0.0f};
            if (!memtile || kt == 0) {
                bf16x8 k0 = *(const bf16x8*)&k_s[kt * 16 + lc][lg * 8];
                bf16x8 k1 = *(const bf16x8*)&k_s[kt * 16 + lc][32 + lg * 8];
                s = __builtin_amdgcn_mfma_f32_16x16x32_bf16(qfr[0], k0, s, 0, 0, 0);
                s = __builtin_amdgcn_mfma_f32_16x16x32_bf16(qfr[1], k1, s, 0, 0, 0);
            }
#pragma unroll
            for (int reg = 0; reg < 4; ++reg) {
                int qi = qb + lg * 4 + reg;
                if (memtile) {
                    sc[kt][reg] = (kt == 0 && lc < KT_) ? s[reg] * 0.125f : -INFINITY;
                } else {
                    int jg = j0 + kt * 16 + lc;
                    bool vis = (jg <= qi) && (am[kt] > 0);
                    sc[kt][reg] = vis ? (s[reg] * 0.125f - slope * (float)(qi - jg)) : -INFINITY;
                }
            }
        }

        // ---- online softmax (register-resident, 16-lane shuffle reduce) ----
        float pv_[4][4];
#pragma unroll
        for (int reg = 0; reg < 4; ++reg) {
            float tm = fmaxf(fmaxf(sc[0][reg], sc[1][reg]), fmaxf(sc[2][reg], sc[3][reg]));
#pragma unroll
            for (int msk = 1; msk <= 8; msk <<= 1) tm = fmaxf(tm, __shfl_xor(tm, msk));
            float mnew = fmaxf(mrow[reg], tm);
            fac[reg] = __expf(mrow[reg] - mnew);
            mrow[reg] = mnew;
            float rs = 0.0f;
#pragma unroll
            for (int kt = 0; kt < 4; ++kt) {
                float p = __expf(sc[kt][reg] - mnew);
                pv_[kt][reg] = p;
                rs += p;
            }
#pragma unroll
            for (int msk = 1; msk <= 8; msk <<= 1) rs += __shfl_xor(rs, msk);
            lrow[reg] = lrow[reg] * fac[reg] + rs;
        }

        // ---- write P to per-wave LDS as bf16 pairs ----
        int parity = l & 1;
        int ktw = memtile ? 2 : 4;
        for (int kt = 0; kt < ktw; ++kt) {
#pragma unroll
            for (int rp = 0; rp < 4; rp += 2) {
                float s0 = (memtile && kt == 1) ? 0.0f : pv_[kt][rp];
                float s1 = (memtile && kt == 1) ? 0.0f : pv_[kt][rp + 1];
                float o0 = __shfl_xor(s0, 1);
                float o1 = __shfl_xor(s1, 1);
                float lo, hi; int reg;
                if (parity == 0) { lo = s0; hi = o0; reg = rp; }
                else             { lo = o1; hi = s1; reg = rp + 1; }
                unsigned pk = (unsigned)f2bf(lo) | ((unsigned)f2bf(hi) << 16);
                *(unsigned*)&p_s[w][lg * 4 + reg][kt * 16 + (lc & ~1)] = pk;
            }
        }
        __syncthreads();

        // ---- PV accumulate ----
#pragma unroll
        for (int db = 0; db < 4; ++db) {
#pragma unroll
            for (int reg = 0; reg < 4; ++reg) O[db][reg] *= fac[reg];
        }
        int nkh = memtile ? 1 : 2;
        for (int kh = 0; kh < nkh; ++kh) {
            bf16x8 a = *(const bf16x8*)&p_s[w][lc][kh * 32 + lg * 8];
#pragma unroll
            for (int db = 0; db < 4; ++db) {
                bf16x8 vb = *(const bf16x8*)&vT_s[db * 16 + lc][kh * 32 + lg * 8];
                O[db] = __builtin_amdgcn_mfma_f32_16x16x32_bf16(a, vb, O[db], 0, 0, 0);
            }
        }
    }

    // ---- epilogue: write bf16 h/m splits of attention output ----
#pragma unroll
    for (int db = 0; db < 4; ++db) {
#pragma unroll
        for (int reg = 0; reg < 4; ++reg) {
            int qi = qb + lg * 4 + reg;
            size_t idx = ((size_t)(b * S_ + qi)) * D_ + h * DH_ + db * 16 + lc;
            float o = O[db][reg] / lrow[reg];
            unsigned short hb = f2bf(o);
            float hf = bf2f(hb);
            unsigned short mb = f2bf(o - hf);
            AOh[idx] = (short)hb;
            AOm[idx] = (short)mb;
        }
    }
}

// ---------------- launch ----------------
extern "C" void kernel_launch(void* const* d_in, const int* in_sizes, int n_in,
                              void* d_out, int out_size, void* d_ws, size_t ws_size,
                              hipStream_t stream)
{
    const float* X = (const float*)d_in[0];
    const int* amask = (const int*)d_in[1];
    const float* Wq = (const float*)d_in[2];
    const float* Wk = (const float*)d_in[3];
    const float* Wv = (const float*)d_in[4];
    const float* Wo = (const float*)d_in[5];
    float* out = (float*)d_out;

    char* p = (char*)d_ws;
    auto alloc = [&](size_t bytes) -> char* {
        char* r = p; p += (bytes + 255) & ~(size_t)255; return r;
    };
    double* sur = (double*)alloc((size_t)B_ * S_ * sizeof(double));
    float* kacc = (float*)alloc((size_t)2 * BS_ * D_ * sizeof(float));  // kf | kp1
    float* events = (float*)alloc((size_t)EVCAP_ * D_ * sizeof(float)); // = BS*D f32, reused as O partial2
    float* ret = (float*)alloc((size_t)B_ * KT_ * D_ * sizeof(float));
    float* sims = (float*)alloc(MEM_ * sizeof(float));
    int* seg_start = (int*)alloc(S_ * sizeof(int));
    int* seg_end = (int*)alloc(S_ * sizeof(int));
    int* scal = (int*)alloc(64);
    short* qbf = (short*)alloc((size_t)BS_ * D_ * sizeof(short));   // qbf|vbf span reused as O partial3
    short* vbf = (short*)alloc((size_t)BS_ * D_ * sizeof(short));
    short* vbfT = (short*)alloc((size_t)B_ * H_ * DH_ * S_ * sizeof(short));
    short* Xh = (short*)alloc((size_t)BS_ * D_ * sizeof(short));   // reused as AOh
    short* Xm = (short*)alloc((size_t)BS_ * D_ * sizeof(short));   // reused as AOm
    short* Xl = (short*)alloc((size_t)BS_ * D_ * sizeof(short));   // reused as kbf
    short* Wqh = (short*)alloc((size_t)D_ * D_ * sizeof(short));
    short* Wqm = (short*)alloc((size_t)D_ * D_ * sizeof(short));
    short* Wvh = (short*)alloc((size_t)D_ * D_ * sizeof(short));
    short* Wvm = (short*)alloc((size_t)D_ * D_ * sizeof(short));
    short* Woh = (short*)alloc((size_t)D_ * D_ * sizeof(short));
    short* Wom = (short*)alloc((size_t)D_ * D_ * sizeof(short));
    short* Wkh = (short*)alloc((size_t)D_ * D_ * sizeof(short));
    short* Wkm = (short*)alloc((size_t)D_ * D_ * sizeof(short));
    short* Wkl = (short*)alloc((size_t)D_ * D_ * sizeof(short));
    if ((size_t)(p - (char*)d_ws) > ws_size) return;  // insufficient workspace

    float* kf = kacc;
    float* kp1 = kacc + (size_t)BS_ * D_;
    short* kbf = Xl;

    init_counters<<<1, 1, 0, stream>>>(scal);

    int nx4 = BS_ * D_ / 4;
    int nw4 = D_ * D_ / 4;
    split_f32_kernel<true><<<(nx4 + 255) / 256, 256, 0, stream>>>(X, Xh, Xm, Xl, nx4);
    split_f32_kernel<false><<<(nw4 + 255) / 256, 256, 0, stream>>>(Wq, Wqh, Wqm, nullptr, nw4);
    split_f32_kernel<true><<<(nw4 + 255) / 256, 256, 0, stream>>>(Wk, Wkh, Wkm, Wkl, nw4);
    split_f32_kernel<false><<<(nw4 + 255) / 256, 256, 0, stream>>>(Wv, Wvh, Wvm, nullptr, nw4);
    split_f32_kernel<false><<<(nw4 + 255) / 256, 256, 0, stream>>>(Wo, Woh, Wom, nullptr, nw4);

    // Fused QV + K(split-K 2) GEMM: 4 groups x 8 col-panels x 32 row-panels = 1024 blocks.
    {
        FArgs fa = {};
        fa.A[0][0] = Xm;  fa.A[0][1] = Xh;  fa.A[0][2] = Xh;
        fa.B[0][0] = Wqh; fa.B[0][1] = Wqm; fa.B[0][2] = Wqh;
        fa.outb[0] = qbf;
        fa.A[1][0] = Xm;  fa.A[1][1] = Xh;  fa.A[1][2] = Xh;
        fa.B[1][0] = Wvh; fa.B[1][1] = Wvm; fa.B[1][2] = Wvh;
        fa.outb[1] = vbf;
        fa.A[2][0] = Xh;  fa.A[2][1] = Xm;  fa.A[2][2] = Xm;
        fa.B[2][0] = Wkm; fa.B[2][1] = Wkh; fa.B[2][2] = Wkm;
        fa.outf[2] = kf;
        fa.A[3][0] = Xh;  fa.A[3][1] = Xl;  fa.A[3][2] = Xh;
        fa.B[3][0] = Wkl; fa.B[3][1] = Wkh; fa.B[3][2] = Wkh;
        fa.outf[3] = kp1;
        fa.gsbase[0] = 0; fa.gsbase[1] = 0; fa.gsbase[2] = 0; fa.gsbase[3] = 0;
        fa.nsteps = 48;
        fa.jshift = 5;
        gemm_ms<<<1024, 256, 0, stream>>>(fa);
    }
    transpose_v<<<dim3(S_ / 64, H_, B_), 256, 0, stream>>>(vbf, vbfT);
    addk_kernel<<<BS_ * D_ / 4 / 256, 256, 0, stream>>>(kf, kp1, kbf);

    surprise_kernel<<<dim3(S_, B_), 256, 0, stream>>>(kf, sur);
    for (int b = 0; b < B_; ++b) {
        const float* kfb = kf + (size_t)b * S_ * D_;
        boundary_kernel<<<1, 256, 0, stream>>>(sur + (size_t)b * S_, seg_start, seg_end, scal);
        seg_means_kernel<<<S_, 256, 0, stream>>>(kfb, events, seg_start, seg_end, scal);
        sims_kernel<<<MEM_, 256, 0, stream>>>(events, kfb + (size_t)(S_ - 1) * D_, sims, scal);
        topk_kernel<<<1, 256, 0, stream>>>(events, sims, ret + (size_t)b * KT_ * D_, scal);
    }

    attn_mfma_kernel<<<dim3(S_ / QTT, H_, B_), 256, 0, stream>>>(qbf, kbf, vbfT, ret, amask, Xh, Xm);

    // O GEMM: A = attention-output splits (AOm,AOh,AOh), split-K=4 -> 1024 blocks
    {
        float* p2 = events;
        float* p3 = (float*)qbf;   // qbf|vbf span (contiguous, 16 MB) — dead after attn
        FArgs fa = {};
        for (int g = 0; g < 4; ++g) {
            fa.A[g][0] = Xm;  fa.A[g][1] = Xh;  fa.A[g][2] = Xh;
            fa.B[g][0] = Woh; fa.B[g][1] = Wom; fa.B[g][2] = Woh;
        }
        fa.outf[0] = kf; fa.outf[1] = kp1; fa.outf[2] = p2; fa.outf[3] = p3;
        fa.gsbase[0] = 0; fa.gsbase[1] = 12; fa.gsbase[2] = 24; fa.gsbase[3] = 36;
        fa.nsteps = 12;
        fa.jshift = 5;
        gemm_ms<<<1024, 256, 0, stream>>>(fa);
        addo4_kernel<<<BS_ * D_ / 4 / 256, 256, 0, stream>>>(kf, kp1, p2, p3, out);
    }
}

// Round 9
// 531.433 us; speedup vs baseline: 1.1215x; 1.1215x over previous
//
#include <hip/hip_runtime.h>
#include <math.h>

#define B_ 2
#define S_ 2048
#define H_ 16
#define DH_ 64
#define D_ 1024
#define MEM_ 1000
#define KT_ 10
#define THRESH_ 0.5
#define BS_ (B_ * S_)
#define EVCAP_ (2 * S_)   // max possible events (<= S per sample)

typedef float f32x4 __attribute__((ext_vector_type(4)));
typedef short bf16x8 __attribute__((ext_vector_type(8)));
typedef short s16x4 __attribute__((ext_vector_type(4)));

__device__ inline unsigned short f2bf(float f) {
    union { float f; unsigned u; } v; v.f = f;
    unsigned u = v.u;
    unsigned r = (u + 0x7FFFu + ((u >> 16) & 1u)) >> 16;  // RNE
    return (unsigned short)r;
}
__device__ inline float bf2f(unsigned short h) {
    union { unsigned u; float f; } v; v.u = ((unsigned)h) << 16; return v.f;
}

// async global->LDS, 16B per lane; LDS dest = wave-uniform base + lane*16
__device__ __forceinline__ void gload16(const short* gp, const short* lp) {
    __builtin_amdgcn_global_load_lds(
        (__attribute__((address_space(1))) void*)(unsigned long long)gp,
        (__attribute__((address_space(3))) void*)(unsigned)(unsigned long long)lp,
        16, 0, 0);
}

// ---------------- init ----------------
__global__ void init_counters(int* scal) { scal[0] = 0; scal[1] = 0; scal[2] = 0; }

// ---------------- split f32 -> bf16 chunks (h, m, optional l) ----------------
template <bool WL>
__global__ __launch_bounds__(256) void split_f32_kernel(const float* __restrict__ src,
                                                        short* __restrict__ h,
                                                        short* __restrict__ m,
                                                        short* __restrict__ l,
                                                        int n4)
{
    int i = blockIdx.x * 256 + threadIdx.x;
    if (i >= n4) return;
    float4 x = ((const float4*)src)[i];
    float xs[4] = {x.x, x.y, x.z, x.w};
    s16x4 hv, mv, lv;
#pragma unroll
    for (int j = 0; j < 4; ++j) {
        unsigned short hb = f2bf(xs[j]);
        float hf = bf2f(hb);
        float r1 = xs[j] - hf;            // exact in f32
        unsigned short mb = f2bf(r1);
        hv[j] = (short)hb; mv[j] = (short)mb;
        if (WL) {
            float mf = bf2f(mb);
            lv[j] = (short)f2bf(r1 - mf); // exact residual, rounded
        }
    }
    ((s16x4*)h)[i] = hv;
    ((s16x4*)m)[i] = mv;
    if (WL) ((s16x4*)l)[i] = lv;
}

// ---------------- multi-job 128x128 split-precision bf16 MFMA GEMM -----------
struct FArgs {
    const short* A[4][3];   // per-group A term pointers (term id = gs>>4)
    const short* B[4][3];
    short* outb[4];         // bf16 output (or null)
    float* outf[4];         // f32 output (used when outb[g]==null)
    int gsbase[4];          // global K-step base per group
    int nsteps;             // K-steps per block
    int jshift;             // log2(ngroups*8)
};

__global__ __launch_bounds__(256) void gemm_ms(FArgs fa)
{
    __shared__ __align__(16) short As[128 * 64];
    __shared__ __align__(16) short Bs[128 * 64];
    int wg = blockIdx.x;
    int q = gridDim.x >> 3;
    int lin = (wg & 7) * q + (wg >> 3);      // XCD-clustered linear id
    int by = lin >> fa.jshift;               // row panel 0..31
    int jb = lin & ((1 << fa.jshift) - 1);
    int g = jb >> 3;                         // job group
    int bcol = jb & 7;                       // col panel 0..7

    int tid = threadIdx.x;
    int w = tid >> 6, l = tid & 63;
    int wr = w >> 1, wc = w & 1;
    int lg = l >> 4, lc = l & 15;
    int jr = l >> 3;        // row within 8-row chunk
    int jc = l & 7;         // 16B col unit (8 shorts)
    int gs0 = fa.gsbase[g];

    f32x4 acc[4][4] = {};

    for (int s = 0; s < fa.nsteps; ++s) {
        int gs = gs0 + s;
        int t = gs >> 4;
        int k0 = (gs & 15) << 6;
        const short* Abase = fa.A[g][t] + (size_t)(by * 128) * D_ + k0 + jc * 8;
        const short* Bbase = fa.B[g][t] + (size_t)(bcol * 128) * D_ + k0 + jc * 8;
        __syncthreads();    // previous compute done reading LDS
#pragma unroll
        for (int i = 0; i < 4; ++i) {
            int chunk = w * 4 + i;
            int row = chunk * 8 + jr;
            gload16(Abase + (size_t)row * D_, As + chunk * 512);
            gload16(Bbase + (size_t)row * D_, Bs + chunk * 512);
        }
        __syncthreads();    // vmcnt(0) drained -> tile ready
#pragma unroll
        for (int kh = 0; kh < 2; ++kh) {
            bf16x8 av[4], bv[4];
#pragma unroll
            for (int mf = 0; mf < 4; ++mf)
                av[mf] = *(const bf16x8*)&As[(wr * 64 + mf * 16 + lc) * 64 + kh * 32 + lg * 8];
#pragma unroll
            for (int nf = 0; nf < 4; ++nf)
                bv[nf] = *(const bf16x8*)&Bs[(wc * 64 + nf * 16 + lc) * 64 + kh * 32 + lg * 8];
#pragma unroll
            for (int mf = 0; mf < 4; ++mf)
#pragma unroll
                for (int nf = 0; nf < 4; ++nf)
                    acc[mf][nf] = __builtin_amdgcn_mfma_f32_16x16x32_bf16(av[mf], bv[nf], acc[mf][nf], 0, 0, 0);
        }
    }

    if (fa.outb[g]) {
        short* ob = fa.outb[g];
#pragma unroll
        for (int mf = 0; mf < 4; ++mf)
#pragma unroll
            for (int nf = 0; nf < 4; ++nf)
#pragma unroll
                for (int reg = 0; reg < 4; ++reg) {
                    int row = by * 128 + wr * 64 + mf * 16 + lg * 4 + reg;
                    int col = bcol * 128 + wc * 64 + nf * 16 + lc;
                    ob[(size_t)row * D_ + col] = (short)f2bf(acc[mf][nf][reg]);
                }
    } else {
        float* of = fa.outf[g];
#pragma unroll
        for (int mf = 0; mf < 4; ++mf)
#pragma unroll
            for (int nf = 0; nf < 4; ++nf)
#pragma unroll
                for (int reg = 0; reg < 4; ++reg) {
                    int row = by * 128 + wr * 64 + mf * 16 + lg * 4 + reg;
                    int col = bcol * 128 + wc * 64 + nf * 16 + lc;
                    of[(size_t)row * D_ + col] = acc[mf][nf][reg];
                }
    }
}

// ---------------- V transpose: vbf[token][d] -> vbfT[b*H+h][d][token] ----------
__global__ __launch_bounds__(256) void transpose_v(const short* __restrict__ vbf,
                                                   short* __restrict__ vbfT)
{
    __shared__ short st[64][70];
    int s0 = blockIdx.x * 64;        // token tile within batch
    int h = blockIdx.y;              // head (d tile = h*64)
    int b = blockIdx.z;
    int tid = threadIdx.x;
    int r = tid >> 2, cb = (tid & 3) * 16;
    const short* src = vbf + (size_t)(b * S_ + s0 + r) * D_ + h * DH_ + cb;
    *(bf16x8*)&st[r][cb] = *(const bf16x8*)src;
    *(bf16x8*)&st[r][cb + 8] = *(const bf16x8*)(src + 8);
    __syncthreads();
    int c = tid >> 2, sb = (tid & 3) * 16;
    short tmp[16];
#pragma unroll
    for (int i = 0; i < 16; ++i) tmp[i] = st[sb + i][c];
    short* dst = vbfT + ((size_t)(b * H_ + h) * DH_ + c) * S_ + s0 + sb;
    *(bf16x8*)dst = *(bf16x8*)&tmp[0];
    *(bf16x8*)(dst + 8) = *(bf16x8*)&tmp[8];
}

// ---------------- split-K adds ----------------
__global__ __launch_bounds__(256) void addk_kernel(float* __restrict__ kf,
                                                   const float* __restrict__ kp1,
                                                   short* __restrict__ kbf)
{
    size_t i = (size_t)blockIdx.x * 256 + threadIdx.x;
    float4 a = ((const float4*)kf)[i];
    float4 b = ((const float4*)kp1)[i];
    float4 s = {a.x + b.x, a.y + b.y, a.z + b.z, a.w + b.w};
    ((float4*)kf)[i] = s;
    s16x4 o;
    o[0] = (short)f2bf(s.x); o[1] = (short)f2bf(s.y);
    o[2] = (short)f2bf(s.z); o[3] = (short)f2bf(s.w);
    ((s16x4*)kbf)[i] = o;
}

__global__ __launch_bounds__(256) void addo_kernel(const float* __restrict__ p0,
                                                   const float* __restrict__ p1,
                                                   float* __restrict__ out)
{
    size_t i = (size_t)blockIdx.x * 256 + threadIdx.x;
    float4 a = ((const float4*)p0)[i];
    float4 b = ((const float4*)p1)[i];
    float4 s = {a.x + b.x, a.y + b.y, a.z + b.z, a.w + b.w};
    ((float4*)out)[i] = s;
}

// ---------------- surprise (both batches): sur[b][t] = ||kf[t]-kf[t-1]|| ----------
__global__ __launch_bounds__(256) void surprise_kernel(const float* __restrict__ kf,
                                                       double* __restrict__ sur)
{
    int t = blockIdx.x;
    int b = blockIdx.y;
    if (t == 0) { if (threadIdx.x == 0) sur[(size_t)b * S_] = 0.0; return; }
    const float* kfb = kf + (size_t)b * S_ * D_;
    __shared__ double red[256];
    double acc = 0.0;
    for (int d = threadIdx.x; d < D_; d += 256) {
        double df = (double)kfb[(size_t)t * D_ + d] - (double)kfb[(size_t)(t - 1) * D_ + d];
        acc += df * df;
    }
    red[threadIdx.x] = acc;
    __syncthreads();
    for (int s = 128; s > 0; s >>= 1) {
        if (threadIdx.x < s) red[threadIdx.x] += red[threadIdx.x + s];
        __syncthreads();
    }
    if (threadIdx.x == 0) sur[(size_t)b * S_ + t] = sqrt(red[0]);
}

// ---------------- boundaries (parallel flags + prefix scan) ----------------
__global__ __launch_bounds__(256) void boundary_kernel(const double* __restrict__ sur,
                                                       int* __restrict__ seg_start,
                                                       int* __restrict__ seg_end,
                                                       int* __restrict__ scal)
{
    __shared__ double lsur[S_];
    __shared__ double red[256];
    __shared__ double sh_mean, sh_thr;
    __shared__ int cnt[256];
    int tid = threadIdx.x;
    for (int t = tid; t < S_; t += 256) lsur[t] = sur[t];
    __syncthreads();
    double a = 0.0;
    for (int t = tid; t < S_; t += 256) a += lsur[t];
    red[tid] = a;
    __syncthreads();
    for (int s = 128; s > 0; s >>= 1) {
        if (tid < s) red[tid] += red[tid + s];
        __syncthreads();
    }
    if (tid == 0) sh_mean = red[0] / (double)S_;
    __syncthreads();
    double mean = sh_mean;
    a = 0.0;
    for (int t = tid; t < S_; t += 256) { double d = lsur[t] - mean; a += d * d; }
    red[tid] = a;
    __syncthreads();
    for (int s = 128; s > 0; s >>= 1) {
        if (tid < s) red[tid] += red[tid + s];
        __syncthreads();
    }
    if (tid == 0) sh_thr = mean + THRESH_ * sqrt(red[0] / (double)(S_ - 1));
    __syncthreads();
    double thr = sh_thr;
    bool flg[8];
    int c = 0;
#pragma unroll
    for (int j = 0; j < 8; ++j) {
        int t = tid * 8 + j;
        flg[j] = (lsur[t] > thr) || (t == S_ - 1);
        c += flg[j] ? 1 : 0;
    }
    cnt[tid] = c;
    __syncthreads();
    for (int off = 1; off < 256; off <<= 1) {   // Hillis-Steele inclusive scan
        int v = cnt[tid];
        int add = (tid >= off) ? cnt[tid - off] : 0;
        __syncthreads();
        cnt[tid] = v + add;
        __syncthreads();
    }
    int r = (tid == 0) ? 0 : cnt[tid - 1];
#pragma unroll
    for (int j = 0; j < 8; ++j) {
        if (flg[j]) { seg_end[r] = tid * 8 + j; ++r; }
    }
    __syncthreads();
    int n = cnt[255];
    for (int i = tid; i < n; i += 256)
        seg_start[i] = (i == 0) ? 0 : seg_end[i - 1] + 1;
    if (tid == 0) {
        scal[1] = n;         // nseg
        scal[2] = scal[0];   // ev_base
        scal[0] += n;        // ev_count
    }
}

// ---------------- segment means -> append events ----------------
__global__ __launch_bounds__(256) void seg_means_kernel(const float* __restrict__ kfb,
                                                        float* __restrict__ events,
                                                        const int* __restrict__ seg_start,
                                                        const int* __restrict__ seg_end,
                                                        const int* __restrict__ scal)
{
    int g = blockIdx.x;
    if (g >= scal[1]) return;
    int s = seg_start[g], e = seg_end[g];
    double inv = 1.0 / (double)(e - s + 1);
    size_t obase = (size_t)(scal[2] + g) * D_;
    for (int d = threadIdx.x; d < D_; d += 256) {
        double acc = 0.0;
        for (int r = s; r <= e; ++r) acc += (double)kfb[(size_t)r * D_ + d];
        events[obase + d] = (float)(acc * inv);
    }
}

// ---------------- cosine sims of memory window vs last key ----------------
__global__ __launch_bounds__(256) void sims_kernel(const float* __restrict__ events,
                                                   const float* __restrict__ q,
                                                   float* __restrict__ sims,
                                                   const int* __restrict__ scal)
{
    int e = blockIdx.x;
    int total = scal[0];
    int w = total < MEM_ ? total : MEM_;
    if (e >= w) { if (threadIdx.x == 0) sims[e] = -INFINITY; return; }
    int wstart = total - w;
    const float* ev = events + (size_t)(wstart + e) * D_;
    __shared__ double r1[256], r2[256], r3[256];
    int tid = threadIdx.x;
    double dot = 0.0, n2 = 0.0, q2 = 0.0;
    for (int d = tid; d < D_; d += 256) {
        double ed = ev[d], qd = q[d];
        dot += ed * qd; n2 += ed * ed; q2 += qd * qd;
    }
    r1[tid] = dot; r2[tid] = n2; r3[tid] = q2;
    __syncthreads();
    for (int s = 128; s > 0; s >>= 1) {
        if (tid < s) { r1[tid] += r1[tid + s]; r2[tid] += r2[tid + s]; r3[tid] += r3[tid + s]; }
        __syncthreads();
    }
    if (tid == 0) {
        double mn = sqrt(r2[0]); if (mn < 1e-8) mn = 1e-8;
        double qn = sqrt(r3[0]); if (qn < 1e-8) qn = 1e-8;
        sims[e] = (float)(r1[0] / (mn * qn));
    }
}

// ---------------- top-KT selection + gather (tie -> lower index, like lax.top_k) ----------------
__global__ __launch_bounds__(256) void topk_kernel(const float* __restrict__ events,
                                                   float* __restrict__ sims,
                                                   float* __restrict__ retb,
                                                   const int* __restrict__ scal)
{
    int total = scal[0];
    int w = total < MEM_ ? total : MEM_;
    int wstart = total - w;
    __shared__ float bv[256];
    __shared__ int bidx[256];
    __shared__ int chosen;
    int tid = threadIdx.x;
    for (int r = 0; r < KT_; ++r) {
        float best = -INFINITY;
        int bi = 0x7fffffff;
        for (int e = tid; e < w; e += 256) {
            float v = sims[e];
            if (v > best || (v == best && e < bi)) { best = v; bi = e; }
        }
        bv[tid] = best; bidx[tid] = bi;
        __syncthreads();
        for (int s = 128; s > 0; s >>= 1) {
            if (tid < s) {
                if (bv[tid + s] > bv[tid] || (bv[tid + s] == bv[tid] && bidx[tid + s] < bidx[tid])) {
                    bv[tid] = bv[tid + s]; bidx[tid] = bidx[tid + s];
                }
            }
            __syncthreads();
        }
        if (tid == 0) {
            chosen = (r < w) ? bidx[0] : -1;
            if (chosen >= 0) sims[chosen] = -INFINITY;
        }
        __syncthreads();
        int c = chosen;
        if (c >= 0) {
            const float* ev = events + (size_t)(wstart + c) * D_;
            for (int d = tid; d < D_; d += 256) retb[(size_t)r * D_ + d] = ev[d];
        } else {
            for (int d = tid; d < D_; d += 256) retb[(size_t)r * D_ + d] = 0.0f;
        }
        __syncthreads();
    }
}

// ---------------- attention: bf16 MFMA flash, pre-transposed V, XCD-clustered ----
#define QTT 64
#define KTT 64
__global__ __launch_bounds__(256, 8) void attn_mfma_kernel(const short* __restrict__ qbf,
                                                           const short* __restrict__ kbf,
                                                           const short* __restrict__ vbfT,
                                                           const float* __restrict__ ret,
                                                           const int* __restrict__ amask,
                                                           short* __restrict__ AOh,
                                                           short* __restrict__ AOm)
{
    __shared__ __align__(16) short k_s[KTT][72];
    __shared__ __align__(16) short vT_s[DH_][72];
    __shared__ __align__(16) short p_s[4][16][72];

    // XCD-clustered decode: each XCD owns 4 contiguous (h,b) pairs x all 32 qt.
    int bid = blockIdx.x;
    int job = (bid & 7) * 128 + (bid >> 3);
    int hb = job >> 5;
    int h = hb & 15, b = hb >> 4;
    int qt = 31 - (job & 31);               // heavy (large-qt) first within chunk
    int q0 = qt * QTT;
    int tid = threadIdx.x;
    int w = tid >> 6, l = tid & 63;
    int lg = l >> 4, lc = l & 15;
    int qb = q0 + w * 16;
    float slope = exp2f(-0.5f * (float)(h + 1));

    bf16x8 qfr[2];
#pragma unroll
    for (int half = 0; half < 2; ++half)
        qfr[half] = *(const bf16x8*)(qbf + ((size_t)(b * S_ + qb + lc)) * D_ + h * DH_ + half * 32 + lg * 8);

    float mrow[4], lrow[4], fac[4];
#pragma unroll
    for (int r = 0; r < 4; ++r) { mrow[r] = -INFINITY; lrow[r] = 0.0f; }
    f32x4 O[4] = {};

    int sr = tid >> 2;              // staging row (K: key; V: d)
    int sc0 = (tid & 3) * 16;       // staging col base (K: d; V: key)

    int nreal = qt + 1;
    for (int tile = 0; tile <= nreal; ++tile) {
        bool memtile = (tile == nreal);
        int j0 = tile * KTT;
        __syncthreads();   // protect LDS from previous iteration's readers
        if (!memtile) {
            const short* kp = kbf + ((size_t)(b * S_ + j0 + sr)) * D_ + h * DH_ + sc0;
            *(bf16x8*)&k_s[sr][sc0] = *(const bf16x8*)kp;
            *(bf16x8*)&k_s[sr][sc0 + 8] = *(const bf16x8*)(kp + 8);
            const short* vp = vbfT + ((size_t)(b * H_ + h) * DH_ + sr) * S_ + j0 + sc0;
            *(bf16x8*)&vT_s[sr][sc0] = *(const bf16x8*)vp;
            *(bf16x8*)&vT_s[sr][sc0 + 8] = *(const bf16x8*)(vp + 8);
        } else {
            short kv[16];
            if (sr < KT_) {
                const float* rp = ret + ((size_t)(b * KT_ + sr)) * D_ + h * DH_ + sc0;
#pragma unroll
                for (int i = 0; i < 4; ++i) {
                    float4 a = *(const float4*)(rp + i * 4);
                    kv[i * 4 + 0] = (short)f2bf(a.x); kv[i * 4 + 1] = (short)f2bf(a.y);
                    kv[i * 4 + 2] = (short)f2bf(a.z); kv[i * 4 + 3] = (short)f2bf(a.w);
                }
            } else {
#pragma unroll
                for (int i = 0; i < 16; ++i) kv[i] = 0;
            }
            *(bf16x8*)&k_s[sr][sc0] = *(bf16x8*)&kv[0];
            *(bf16x8*)&k_s[sr][sc0 + 8] = *(bf16x8*)&kv[8];
        }
        __syncthreads();   // k_s (and vT_s if real tile) ready
        if (memtile) {
            // vT_s[d][key] = k_s[key][d] via in-LDS transpose (32-bit addressing,
            // no global gather: identical bits, far lower register pressure).
            short tv[16];
#pragma unroll
            for (int i = 0; i < 16; ++i) {
                int key = sc0 + i;
                tv[i] = (key < KT_) ? k_s[key][sr] : (short)0;
            }
            *(bf16x8*)&vT_s[sr][sc0] = *(bf16x8*)&tv[0];
            *(bf16x8*)&vT_s[sr][sc0 + 8] = *(bf16x8*)&tv[8];
            // visible to PV by the p_s __syncthreads below
        }

        // ---- QK^T scores (C: row = lg*4+reg = query, col = lc = key) ----
        float sc[4][4];
        int am[4];
        if (!memtile) {
#pragma unroll
            for (int kt = 0; kt < 4; ++kt) am[kt] = amask[b * S_ + j0 + kt * 16 + lc];
        }
#pragma unroll
        for (int kt = 0; kt < 4; ++kt) {
            f32x4 s = {0.0f, 0.0f, 0.0f, 0.0f};
            if (!memtile || kt == 0) {
                bf16x8 k0 = *(const bf16x8*)&k_s[kt * 16 + lc][lg * 8];
                bf16x8 k1 = *(const bf16x8*)&k_s[kt * 16 + lc][32 + lg * 8];
                s = __builtin_amdgcn_mfma_f32_16x16x32_bf16(qfr[0], k0, s, 0, 0, 0);
                s = __builtin_amdgcn_mfma_f32_16x16x32_bf16(qfr[1], k1, s, 0, 0, 0);
            }
#pragma unroll
            for (int reg = 0; reg < 4; ++reg) {
                int qi = qb + lg * 4 + reg;
                if (memtile) {
                    sc[kt][reg] = (kt == 0 && lc < KT_) ? s[reg] * 0.125f : -INFINITY;
                } else {
                    int jg = j0 + kt * 16 + lc;
                    bool vis = (jg <= qi) && (am[kt] > 0);
                    sc[kt][reg] = vis ? (s[reg] * 0.125f - slope * (float)(qi - jg)) : -INFINITY;
                }
            }
        }

        // ---- online softmax (register-resident, 16-lane shuffle reduce) ----
        float pv_[4][4];
#pragma unroll
        for (int reg = 0; reg < 4; ++reg) {
            float tm = fmaxf(fmaxf(sc[0][reg], sc[1][reg]), fmaxf(sc[2][reg], sc[3][reg]));
#pragma unroll
            for (int msk = 1; msk <= 8; msk <<= 1) tm = fmaxf(tm, __shfl_xor(tm, msk));
            float mnew = fmaxf(mrow[reg], tm);
            fac[reg] = __expf(mrow[reg] - mnew);
            mrow[reg] = mnew;
            float rs = 0.0f;
#pragma unroll
            for (int kt = 0; kt < 4; ++kt) {
                float p = __expf(sc[kt][reg] - mnew);
                pv_[kt][reg] = p;
                rs += p;
            }
#pragma unroll
            for (int msk = 1; msk <= 8; msk <<= 1) rs += __shfl_xor(rs, msk);
            lrow[reg] = lrow[reg] * fac[reg] + rs;
        }

        // ---- write P to per-wave LDS as bf16 pairs ----
        int parity = l & 1;
        int ktw = memtile ? 2 : 4;
        for (int kt = 0; kt < ktw; ++kt) {
#pragma unroll
            for (int rp = 0; rp < 4; rp += 2) {
                float s0 = (memtile && kt == 1) ? 0.0f : pv_[kt][rp];
                float s1 = (memtile && kt == 1) ? 0.0f : pv_[kt][rp + 1];
                float o0 = __shfl_xor(s0, 1);
                float o1 = __shfl_xor(s1, 1);
                float lo, hi; int reg;
                if (parity == 0) { lo = s0; hi = o0; reg = rp; }
                else             { lo = o1; hi = s1; reg = rp + 1; }
                unsigned pk = (unsigned)f2bf(lo) | ((unsigned)f2bf(hi) << 16);
                *(unsigned*)&p_s[w][lg * 4 + reg][kt * 16 + (lc & ~1)] = pk;
            }
        }
        __syncthreads();   // p_s + (memtile vT_s) ready

        // ---- PV accumulate ----
#pragma unroll
        for (int db = 0; db < 4; ++db) {
#pragma unroll
            for (int reg = 0; reg < 4; ++reg) O[db][reg] *= fac[reg];
        }
        int nkh = memtile ? 1 : 2;
        for (int kh = 0; kh < nkh; ++kh) {
            bf16x8 a = *(const bf16x8*)&p_s[w][lc][kh * 32 + lg * 8];
#pragma unroll
            for (int db = 0; db < 4; ++db) {
                bf16x8 vb = *(const bf16x8*)&vT_s[db * 16 + lc][kh * 32 + lg * 8];
                O[db] = __builtin_amdgcn_mfma_f32_16x16x32_bf16(a, vb, O[db], 0, 0, 0);
            }
        }
    }

    // ---- epilogue: write bf16 h/m splits of attention output ----
#pragma unroll
    for (int db = 0; db < 4; ++db) {
#pragma unroll
        for (int reg = 0; reg < 4; ++reg) {
            int qi = qb + lg * 4 + reg;
            size_t idx = ((size_t)(b * S_ + qi)) * D_ + h * DH_ + db * 16 + lc;
            float o = O[db][reg] / lrow[reg];
            unsigned short hb2 = f2bf(o);
            float hf = bf2f(hb2);
            unsigned short mb = f2bf(o - hf);
            AOh[idx] = (short)hb2;
            AOm[idx] = (short)mb;
        }
    }
}

// ---------------- launch ----------------
extern "C" void kernel_launch(void* const* d_in, const int* in_sizes, int n_in,
                              void* d_out, int out_size, void* d_ws, size_t ws_size,
                              hipStream_t stream)
{
    const float* X = (const float*)d_in[0];
    const int* amask = (const int*)d_in[1];
    const float* Wq = (const float*)d_in[2];
    const float* Wk = (const float*)d_in[3];
    const float* Wv = (const float*)d_in[4];
    const float* Wo = (const float*)d_in[5];
    float* out = (float*)d_out;

    char* p = (char*)d_ws;
    auto alloc = [&](size_t bytes) -> char* {
        char* r = p; p += (bytes + 255) & ~(size_t)255; return r;
    };
    double* sur = (double*)alloc((size_t)B_ * S_ * sizeof(double));
    float* kacc = (float*)alloc((size_t)2 * BS_ * D_ * sizeof(float));  // kf | kp1; reused by O split-K
    float* events = (float*)alloc((size_t)EVCAP_ * D_ * sizeof(float));
    float* ret = (float*)alloc((size_t)B_ * KT_ * D_ * sizeof(float));
    float* sims = (float*)alloc(MEM_ * sizeof(float));
    int* seg_start = (int*)alloc(S_ * sizeof(int));
    int* seg_end = (int*)alloc(S_ * sizeof(int));
    int* scal = (int*)alloc(64);
    short* qbf = (short*)alloc((size_t)BS_ * D_ * sizeof(short));
    short* vbf = (short*)alloc((size_t)BS_ * D_ * sizeof(short));
    short* vbfT = (short*)alloc((size_t)B_ * H_ * DH_ * S_ * sizeof(short));
    short* Xh = (short*)alloc((size_t)BS_ * D_ * sizeof(short));   // reused as AOh
    short* Xm = (short*)alloc((size_t)BS_ * D_ * sizeof(short));   // reused as AOm
    short* Xl = (short*)alloc((size_t)BS_ * D_ * sizeof(short));   // reused as kbf
    short* Wqh = (short*)alloc((size_t)D_ * D_ * sizeof(short));
    short* Wqm = (short*)alloc((size_t)D_ * D_ * sizeof(short));
    short* Wvh = (short*)alloc((size_t)D_ * D_ * sizeof(short));
    short* Wvm = (short*)alloc((size_t)D_ * D_ * sizeof(short));
    short* Woh = (short*)alloc((size_t)D_ * D_ * sizeof(short));
    short* Wom = (short*)alloc((size_t)D_ * D_ * sizeof(short));
    short* Wkh = (short*)alloc((size_t)D_ * D_ * sizeof(short));
    short* Wkm = (short*)alloc((size_t)D_ * D_ * sizeof(short));
    short* Wkl = (short*)alloc((size_t)D_ * D_ * sizeof(short));
    if ((size_t)(p - (char*)d_ws) > ws_size) return;  // insufficient workspace

    float* kf = kacc;
    float* kp1 = kacc + (size_t)BS_ * D_;
    short* kbf = Xl;

    init_counters<<<1, 1, 0, stream>>>(scal);

    int nx4 = BS_ * D_ / 4;
    int nw4 = D_ * D_ / 4;
    split_f32_kernel<true><<<(nx4 + 255) / 256, 256, 0, stream>>>(X, Xh, Xm, Xl, nx4);
    split_f32_kernel<false><<<(nw4 + 255) / 256, 256, 0, stream>>>(Wq, Wqh, Wqm, nullptr, nw4);
    split_f32_kernel<true><<<(nw4 + 255) / 256, 256, 0, stream>>>(Wk, Wkh, Wkm, Wkl, nw4);
    split_f32_kernel<false><<<(nw4 + 255) / 256, 256, 0, stream>>>(Wv, Wvh, Wvm, nullptr, nw4);
    split_f32_kernel<false><<<(nw4 + 255) / 256, 256, 0, stream>>>(Wo, Woh, Wom, nullptr, nw4);

    // Fused QV + K(split-K 2) GEMM: 4 groups x 8 col-panels x 32 row-panels = 1024 blocks.
    {
        FArgs fa = {};
        fa.A[0][0] = Xm;  fa.A[0][1] = Xh;  fa.A[0][2] = Xh;
        fa.B[0][0] = Wqh; fa.B[0][1] = Wqm; fa.B[0][2] = Wqh;
        fa.outb[0] = qbf;
        fa.A[1][0] = Xm;  fa.A[1][1] = Xh;  fa.A[1][2] = Xh;
        fa.B[1][0] = Wvh; fa.B[1][1] = Wvm; fa.B[1][2] = Wvh;
        fa.outb[1] = vbf;
        fa.A[2][0] = Xh;  fa.A[2][1] = Xm;  fa.A[2][2] = Xm;
        fa.B[2][0] = Wkm; fa.B[2][1] = Wkh; fa.B[2][2] = Wkm;
        fa.outf[2] = kf;
        fa.A[3][0] = Xh;  fa.A[3][1] = Xl;  fa.A[3][2] = Xh;
        fa.B[3][0] = Wkl; fa.B[3][1] = Wkh; fa.B[3][2] = Wkh;
        fa.outf[3] = kp1;
        fa.gsbase[0] = 0; fa.gsbase[1] = 0; fa.gsbase[2] = 0; fa.gsbase[3] = 0;
        fa.nsteps = 48;
        fa.jshift = 5;
        gemm_ms<<<1024, 256, 0, stream>>>(fa);
    }
    transpose_v<<<dim3(S_ / 64, H_, B_), 256, 0, stream>>>(vbf, vbfT);
    addk_kernel<<<BS_ * D_ / 4 / 256, 256, 0, stream>>>(kf, kp1, kbf);

    surprise_kernel<<<dim3(S_, B_), 256, 0, stream>>>(kf, sur);
    for (int b = 0; b < B_; ++b) {
        const float* kfb = kf + (size_t)b * S_ * D_;
        boundary_kernel<<<1, 256, 0, stream>>>(sur + (size_t)b * S_, seg_start, seg_end, scal);
        seg_means_kernel<<<S_, 256, 0, stream>>>(kfb, events, seg_start, seg_end, scal);
        sims_kernel<<<MEM_, 256, 0, stream>>>(events, kfb + (size_t)(S_ - 1) * D_, sims, scal);
        topk_kernel<<<1, 256, 0, stream>>>(events, sims, ret + (size_t)b * KT_ * D_, scal);
    }

    attn_mfma_kernel<<<1024, 256, 0, stream>>>(qbf, kbf, vbfT, ret, amask, Xh, Xm);

    // O GEMM: A = attention-output splits (AOm,AOh,AOh), split-K=2, 512 blocks
    {
        FArgs fa = {};
        fa.A[0][0] = Xm;  fa.A[0][1] = Xh;  fa.A[0][2] = Xh;
        fa.B[0][0] = Woh; fa.B[0][1] = Wom; fa.B[0][2] = Woh;
        fa.outf[0] = kf;
        fa.A[1][0] = Xm;  fa.A[1][1] = Xh;  fa.A[1][2] = Xh;
        fa.B[1][0] = Woh; fa.B[1][1] = Wom; fa.B[1][2] = Woh;
        fa.outf[1] = kp1;
        fa.gsbase[0] = 0; fa.gsbase[1] = 24;
        fa.nsteps = 24;
        fa.jshift = 4;
        gemm_ms<<<512, 256, 0, stream>>>(fa);
    }
    addo_kernel<<<BS_ * D_ / 4 / 256, 256, 0, stream>>>(kf, kp1, out);
}

// Round 10
// 490.216 us; speedup vs baseline: 1.2158x; 1.0841x over previous
//
#include <hip/hip_runtime.h>
#include <math.h>

#define B_ 2
#define S_ 2048
#define H_ 16
#define DH_ 64
#define D_ 1024
#define MEM_ 1000
#define KT_ 10
#define THRESH_ 0.5
#define BS_ (B_ * S_)
#define EVCAP_ (2 * S_)   // max possible events (<= S per sample)

typedef float f32x4 __attribute__((ext_vector_type(4)));
typedef short bf16x8 __attribute__((ext_vector_type(8)));
typedef short s16x4 __attribute__((ext_vector_type(4)));

__device__ inline unsigned short f2bf(float f) {
    union { float f; unsigned u; } v; v.f = f;
    unsigned u = v.u;
    unsigned r = (u + 0x7FFFu + ((u >> 16) & 1u)) >> 16;  // RNE
    return (unsigned short)r;
}
__device__ inline float bf2f(unsigned short h) {
    union { unsigned u; float f; } v; v.u = ((unsigned)h) << 16; return v.f;
}

// async global->LDS, 16B per lane; LDS dest = wave-uniform base + lane*16
__device__ __forceinline__ void gload16(const short* gp, const short* lp) {
    __builtin_amdgcn_global_load_lds(
        (__attribute__((address_space(1))) void*)(unsigned long long)gp,
        (__attribute__((address_space(3))) void*)(unsigned)(unsigned long long)lp,
        16, 0, 0);
}

// ---------------- init ----------------
__global__ void init_counters(int* scal) { scal[0] = 0; scal[1] = 0; scal[2] = 0; }

// ---------------- split f32 -> bf16 chunks: X (h, m, l) ----------------
__global__ __launch_bounds__(256) void split_x_kernel(const float* __restrict__ src,
                                                      short* __restrict__ h,
                                                      short* __restrict__ m,
                                                      short* __restrict__ l,
                                                      int n4)
{
    int i = blockIdx.x * 256 + threadIdx.x;
    if (i >= n4) return;
    float4 x = ((const float4*)src)[i];
    float xs[4] = {x.x, x.y, x.z, x.w};
    s16x4 hv, mv, lv;
#pragma unroll
    for (int j = 0; j < 4; ++j) {
        unsigned short hb = f2bf(xs[j]);
        float hf = bf2f(hb);
        float r1 = xs[j] - hf;            // exact in f32
        unsigned short mb = f2bf(r1);
        hv[j] = (short)hb; mv[j] = (short)mb;
        float mf = bf2f(mb);
        lv[j] = (short)f2bf(r1 - mf);     // exact residual, rounded
    }
    ((s16x4*)h)[i] = hv;
    ((s16x4*)m)[i] = mv;
    ((s16x4*)l)[i] = lv;
}

// ---------------- fused weight split: 4 weights in one dispatch ----------------
struct SArgs {
    const float* src[4];
    short* h[4];
    short* m[4];
    short* l[4];   // null -> skip
};
__global__ __launch_bounds__(256) void split_w_kernel(SArgs sa)
{
    int y = blockIdx.y;
    int i = blockIdx.x * 256 + threadIdx.x;   // D*D/4 elements of float4
    float4 x = ((const float4*)sa.src[y])[i];
    float xs[4] = {x.x, x.y, x.z, x.w};
    s16x4 hv, mv, lv;
    bool wl = (sa.l[y] != nullptr);
#pragma unroll
    for (int j = 0; j < 4; ++j) {
        unsigned short hb = f2bf(xs[j]);
        float hf = bf2f(hb);
        float r1 = xs[j] - hf;
        unsigned short mb = f2bf(r1);
        hv[j] = (short)hb; mv[j] = (short)mb;
        if (wl) {
            float mf = bf2f(mb);
            lv[j] = (short)f2bf(r1 - mf);
        }
    }
    ((s16x4*)sa.h[y])[i] = hv;
    ((s16x4*)sa.m[y])[i] = mv;
    if (wl) ((s16x4*)sa.l[y])[i] = lv;
}

// ---------------- multi-job 128x128 split-precision bf16 MFMA GEMM -----------
struct FArgs {
    const short* A[4][3];   // per-group A term pointers (term id = gs>>4)
    const short* B[4][3];
    short* outb[4];         // bf16 output (or null)
    float* outf[4];         // f32 output (used when outb[g]==null)
    int gsbase[4];          // global K-step base per group
    int nsteps;             // K-steps per block
    int jshift;             // log2(ngroups*8)
};

__global__ __launch_bounds__(256) void gemm_ms(FArgs fa)
{
    __shared__ __align__(16) short As[128 * 64];
    __shared__ __align__(16) short Bs[128 * 64];
    int wg = blockIdx.x;
    int q = gridDim.x >> 3;
    int lin = (wg & 7) * q + (wg >> 3);      // XCD-clustered linear id
    int by = lin >> fa.jshift;               // row panel 0..31
    int jb = lin & ((1 << fa.jshift) - 1);
    int g = jb >> 3;                         // job group
    int bcol = jb & 7;                       // col panel 0..7

    int tid = threadIdx.x;
    int w = tid >> 6, l = tid & 63;
    int wr = w >> 1, wc = w & 1;
    int lg = l >> 4, lc = l & 15;
    int jr = l >> 3;        // row within 8-row chunk
    int jc = l & 7;         // 16B col unit (8 shorts)
    int gs0 = fa.gsbase[g];

    f32x4 acc[4][4] = {};

    for (int s = 0; s < fa.nsteps; ++s) {
        int gs = gs0 + s;
        int t = gs >> 4;
        int k0 = (gs & 15) << 6;
        const short* Abase = fa.A[g][t] + (size_t)(by * 128) * D_ + k0 + jc * 8;
        const short* Bbase = fa.B[g][t] + (size_t)(bcol * 128) * D_ + k0 + jc * 8;
        __syncthreads();    // previous compute done reading LDS
#pragma unroll
        for (int i = 0; i < 4; ++i) {
            int chunk = w * 4 + i;
            int row = chunk * 8 + jr;
            gload16(Abase + (size_t)row * D_, As + chunk * 512);
            gload16(Bbase + (size_t)row * D_, Bs + chunk * 512);
        }
        __syncthreads();    // vmcnt(0) drained -> tile ready
#pragma unroll
        for (int kh = 0; kh < 2; ++kh) {
            bf16x8 av[4], bv[4];
#pragma unroll
            for (int mf = 0; mf < 4; ++mf)
                av[mf] = *(const bf16x8*)&As[(wr * 64 + mf * 16 + lc) * 64 + kh * 32 + lg * 8];
#pragma unroll
            for (int nf = 0; nf < 4; ++nf)
                bv[nf] = *(const bf16x8*)&Bs[(wc * 64 + nf * 16 + lc) * 64 + kh * 32 + lg * 8];
#pragma unroll
            for (int mf = 0; mf < 4; ++mf)
#pragma unroll
                for (int nf = 0; nf < 4; ++nf)
                    acc[mf][nf] = __builtin_amdgcn_mfma_f32_16x16x32_bf16(av[mf], bv[nf], acc[mf][nf], 0, 0, 0);
        }
    }

    if (fa.outb[g]) {
        short* ob = fa.outb[g];
#pragma unroll
        for (int mf = 0; mf < 4; ++mf)
#pragma unroll
            for (int nf = 0; nf < 4; ++nf)
#pragma unroll
                for (int reg = 0; reg < 4; ++reg) {
                    int row = by * 128 + wr * 64 + mf * 16 + lg * 4 + reg;
                    int col = bcol * 128 + wc * 64 + nf * 16 + lc;
                    ob[(size_t)row * D_ + col] = (short)f2bf(acc[mf][nf][reg]);
                }
    } else {
        float* of = fa.outf[g];
#pragma unroll
        for (int mf = 0; mf < 4; ++mf)
#pragma unroll
            for (int nf = 0; nf < 4; ++nf)
#pragma unroll
                for (int reg = 0; reg < 4; ++reg) {
                    int row = by * 128 + wr * 64 + mf * 16 + lg * 4 + reg;
                    int col = bcol * 128 + wc * 64 + nf * 16 + lc;
                    of[(size_t)row * D_ + col] = acc[mf][nf][reg];
                }
    }
}

// ---------------- V transpose: vbf[token][d] -> vbfT[b*H+h][d][token] ----------
__global__ __launch_bounds__(256) void transpose_v(const short* __restrict__ vbf,
                                                   short* __restrict__ vbfT)
{
    __shared__ short st[64][70];
    int s0 = blockIdx.x * 64;        // token tile within batch
    int h = blockIdx.y;              // head (d tile = h*64)
    int b = blockIdx.z;
    int tid = threadIdx.x;
    int r = tid >> 2, cb = (tid & 3) * 16;
    const short* src = vbf + (size_t)(b * S_ + s0 + r) * D_ + h * DH_ + cb;
    *(bf16x8*)&st[r][cb] = *(const bf16x8*)src;
    *(bf16x8*)&st[r][cb + 8] = *(const bf16x8*)(src + 8);
    __syncthreads();
    int c = tid >> 2, sb = (tid & 3) * 16;
    short tmp[16];
#pragma unroll
    for (int i = 0; i < 16; ++i) tmp[i] = st[sb + i][c];
    short* dst = vbfT + ((size_t)(b * H_ + h) * DH_ + c) * S_ + s0 + sb;
    *(bf16x8*)dst = *(bf16x8*)&tmp[0];
    *(bf16x8*)(dst + 8) = *(bf16x8*)&tmp[8];
}

// ---------------- split-K adds ----------------
__global__ __launch_bounds__(256) void addk_kernel(float* __restrict__ kf,
                                                   const float* __restrict__ kp1,
                                                   short* __restrict__ kbf)
{
    size_t i = (size_t)blockIdx.x * 256 + threadIdx.x;
    float4 a = ((const float4*)kf)[i];
    float4 b = ((const float4*)kp1)[i];
    float4 s = {a.x + b.x, a.y + b.y, a.z + b.z, a.w + b.w};
    ((float4*)kf)[i] = s;
    s16x4 o;
    o[0] = (short)f2bf(s.x); o[1] = (short)f2bf(s.y);
    o[2] = (short)f2bf(s.z); o[3] = (short)f2bf(s.w);
    ((s16x4*)kbf)[i] = o;
}

__global__ __launch_bounds__(256) void addo_kernel(const float* __restrict__ p0,
                                                   const float* __restrict__ p1,
                                                   float* __restrict__ out)
{
    size_t i = (size_t)blockIdx.x * 256 + threadIdx.x;
    float4 a = ((const float4*)p0)[i];
    float4 b = ((const float4*)p1)[i];
    float4 s = {a.x + b.x, a.y + b.y, a.z + b.z, a.w + b.w};
    ((float4*)out)[i] = s;
}

// ---------------- surprise (both batches): sur[b][t] = ||kf[t]-kf[t-1]|| ----------
__global__ __launch_bounds__(256) void surprise_kernel(const float* __restrict__ kf,
                                                       double* __restrict__ sur)
{
    int t = blockIdx.x;
    int b = blockIdx.y;
    if (t == 0) { if (threadIdx.x == 0) sur[(size_t)b * S_] = 0.0; return; }
    const float* kfb = kf + (size_t)b * S_ * D_;
    __shared__ double red[256];
    double acc = 0.0;
    for (int d = threadIdx.x; d < D_; d += 256) {
        double df = (double)kfb[(size_t)t * D_ + d] - (double)kfb[(size_t)(t - 1) * D_ + d];
        acc += df * df;
    }
    red[threadIdx.x] = acc;
    __syncthreads();
    for (int s = 128; s > 0; s >>= 1) {
        if (threadIdx.x < s) red[threadIdx.x] += red[threadIdx.x + s];
        __syncthreads();
    }
    if (threadIdx.x == 0) sur[(size_t)b * S_ + t] = sqrt(red[0]);
}

// ---------------- boundaries (parallel flags + prefix scan) ----------------
__global__ __launch_bounds__(256) void boundary_kernel(const double* __restrict__ sur,
                                                       int* __restrict__ seg_start,
                                                       int* __restrict__ seg_end,
                                                       int* __restrict__ scal)
{
    __shared__ double lsur[S_];
    __shared__ double red[256];
    __shared__ double sh_mean, sh_thr;
    __shared__ int cnt[256];
    int tid = threadIdx.x;
    for (int t = tid; t < S_; t += 256) lsur[t] = sur[t];
    __syncthreads();
    double a = 0.0;
    for (int t = tid; t < S_; t += 256) a += lsur[t];
    red[tid] = a;
    __syncthreads();
    for (int s = 128; s > 0; s >>= 1) {
        if (tid < s) red[tid] += red[tid + s];
        __syncthreads();
    }
    if (tid == 0) sh_mean = red[0] / (double)S_;
    __syncthreads();
    double mean = sh_mean;
    a = 0.0;
    for (int t = tid; t < S_; t += 256) { double d = lsur[t] - mean; a += d * d; }
    red[tid] = a;
    __syncthreads();
    for (int s = 128; s > 0; s >>= 1) {
        if (tid < s) red[tid] += red[tid + s];
        __syncthreads();
    }
    if (tid == 0) sh_thr = mean + THRESH_ * sqrt(red[0] / (double)(S_ - 1));
    __syncthreads();
    double thr = sh_thr;
    bool flg[8];
    int c = 0;
#pragma unroll
    for (int j = 0; j < 8; ++j) {
        int t = tid * 8 + j;
        flg[j] = (lsur[t] > thr) || (t == S_ - 1);
        c += flg[j] ? 1 : 0;
    }
    cnt[tid] = c;
    __syncthreads();
    for (int off = 1; off < 256; off <<= 1) {   // Hillis-Steele inclusive scan
        int v = cnt[tid];
        int add = (tid >= off) ? cnt[tid - off] : 0;
        __syncthreads();
        cnt[tid] = v + add;
        __syncthreads();
    }
    int r = (tid == 0) ? 0 : cnt[tid - 1];
#pragma unroll
    for (int j = 0; j < 8; ++j) {
        if (flg[j]) { seg_end[r] = tid * 8 + j; ++r; }
    }
    __syncthreads();
    int n = cnt[255];
    for (int i = tid; i < n; i += 256)
        seg_start[i] = (i == 0) ? 0 : seg_end[i - 1] + 1;
    if (tid == 0) {
        scal[1] = n;         // nseg
        scal[2] = scal[0];   // ev_base
        scal[0] += n;        // ev_count
    }
}

// ---------------- segment means -> append events ----------------
__global__ __launch_bounds__(256) void seg_means_kernel(const float* __restrict__ kfb,
                                                        float* __restrict__ events,
                                                        const int* __restrict__ seg_start,
                                                        const int* __restrict__ seg_end,
                                                        const int* __restrict__ scal)
{
    int g = blockIdx.x;
    if (g >= scal[1]) return;
    int s = seg_start[g], e = seg_end[g];
    double inv = 1.0 / (double)(e - s + 1);
    size_t obase = (size_t)(scal[2] + g) * D_;
    for (int d = threadIdx.x; d < D_; d += 256) {
        double acc = 0.0;
        for (int r = s; r <= e; ++r) acc += (double)kfb[(size_t)r * D_ + d];
        events[obase + d] = (float)(acc * inv);
    }
}

// ---------------- cosine sims of memory window vs last key ----------------
__global__ __launch_bounds__(256) void sims_kernel(const float* __restrict__ events,
                                                   const float* __restrict__ q,
                                                   float* __restrict__ sims,
                                                   const int* __restrict__ scal)
{
    int e = blockIdx.x;
    int total = scal[0];
    int w = total < MEM_ ? total : MEM_;
    if (e >= w) { if (threadIdx.x == 0) sims[e] = -INFINITY; return; }
    int wstart = total - w;
    const float* ev = events + (size_t)(wstart + e) * D_;
    __shared__ double r1[256], r2[256], r3[256];
    int tid = threadIdx.x;
    double dot = 0.0, n2 = 0.0, q2 = 0.0;
    for (int d = tid; d < D_; d += 256) {
        double ed = ev[d], qd = q[d];
        dot += ed * qd; n2 += ed * ed; q2 += qd * qd;
    }
    r1[tid] = dot; r2[tid] = n2; r3[tid] = q2;
    __syncthreads();
    for (int s = 128; s > 0; s >>= 1) {
        if (tid < s) { r1[tid] += r1[tid + s]; r2[tid] += r2[tid + s]; r3[tid] += r3[tid + s]; }
        __syncthreads();
    }
    if (tid == 0) {
        double mn = sqrt(r2[0]); if (mn < 1e-8) mn = 1e-8;
        double qn = sqrt(r3[0]); if (qn < 1e-8) qn = 1e-8;
        sims[e] = (float)(r1[0] / (mn * qn));
    }
}

// ---------------- top-KT selection + gather (tie -> lower index, like lax.top_k) ----------------
__global__ __launch_bounds__(256) void topk_kernel(const float* __restrict__ events,
                                                   float* __restrict__ sims,
                                                   float* __restrict__ retb,
                                                   const int* __restrict__ scal)
{
    int total = scal[0];
    int w = total < MEM_ ? total : MEM_;
    int wstart = total - w;
    __shared__ float bv[256];
    __shared__ int bidx[256];
    __shared__ int chosen;
    int tid = threadIdx.x;
    for (int r = 0; r < KT_; ++r) {
        float best = -INFINITY;
        int bi = 0x7fffffff;
        for (int e = tid; e < w; e += 256) {
            float v = sims[e];
            if (v > best || (v == best && e < bi)) { best = v; bi = e; }
        }
        bv[tid] = best; bidx[tid] = bi;
        __syncthreads();
        for (int s = 128; s > 0; s >>= 1) {
            if (tid < s) {
                if (bv[tid + s] > bv[tid] || (bv[tid + s] == bv[tid] && bidx[tid + s] < bidx[tid])) {
                    bv[tid] = bv[tid + s]; bidx[tid] = bidx[tid + s];
                }
            }
            __syncthreads();
        }
        if (tid == 0) {
            chosen = (r < w) ? bidx[0] : -1;
            if (chosen >= 0) sims[chosen] = -INFINITY;
        }
        __syncthreads();
        int c = chosen;
        if (c >= 0) {
            const float* ev = events + (size_t)(wstart + c) * D_;
            for (int d = tid; d < D_; d += 256) retb[(size_t)r * D_ + d] = ev[d];
        } else {
            for (int d = tid; d < D_; d += 256) retb[(size_t)r * D_ + d] = 0.0f;
        }
        __syncthreads();
    }
}

// ---------------- attention: bf16 MFMA flash, QTT=128, 8 waves, load-balanced ----
#define QTT 128
#define KTT 64
__global__ __launch_bounds__(512, 4) void attn_mfma_kernel(const short* __restrict__ qbf,
                                                           const short* __restrict__ kbf,
                                                           const short* __restrict__ vbfT,
                                                           const float* __restrict__ ret,
                                                           const int* __restrict__ amask,
                                                           short* __restrict__ AOh,
                                                           short* __restrict__ AOm)
{
    __shared__ __align__(16) short k_s[KTT][72];
    __shared__ __align__(16) short vT_s[DH_][72];
    __shared__ __align__(16) short p_s[8][16][72];

    // Decode: XCD-clustered (4 hb pairs/XCD) + CU load-balance pairing:
    // jobs idx and idx+32 land on the same CU (round-robin heuristic);
    // qt(s)=15-s / s-8 makes their tile counts sum to a constant 36.
    int bid = blockIdx.x;                    // 0..511
    int xcd = bid & 7;
    int idx = bid >> 3;                      // 0..63
    int qtslot = idx >> 2;                   // 0..15
    int hbL = idx & 3;                       // 0..3
    int qt = (qtslot < 8) ? (15 - qtslot) : (qtslot - 8);
    int hb = xcd * 4 + hbL;                  // 0..31
    int h = hb & 15, b = hb >> 4;
    int q0 = qt * QTT;

    int tid = threadIdx.x;
    int w = tid >> 6, l = tid & 63;          // 8 waves
    int lg = l >> 4, lc = l & 15;
    int qb = q0 + w * 16;                    // this wave's 16 queries
    float slope = exp2f(-0.5f * (float)(h + 1));

    bf16x8 qfr[2];
#pragma unroll
    for (int half = 0; half < 2; ++half)
        qfr[half] = *(const bf16x8*)(qbf + ((size_t)(b * S_ + qb + lc)) * D_ + h * DH_ + half * 32 + lg * 8);

    float mrow[4], lrow[4], fac[4];
#pragma unroll
    for (int r = 0; r < 4; ++r) { mrow[r] = -INFINITY; lrow[r] = 0.0f; }
    f32x4 O[4] = {};

    int sr = tid >> 3;              // staging row (K: key; V: d) 0..63
    int sc0 = (tid & 7) * 8;        // staging col base (8 shorts)

    int ntiles = 2 * (qt + 1);      // real K-tiles; tile==ntiles -> memtile
    for (int tile = 0; tile <= ntiles; ++tile) {
        bool memtile = (tile == ntiles);
        int j0 = tile * KTT;
        __syncthreads();   // protect LDS from previous iteration's readers
        if (!memtile) {
            const short* kp = kbf + ((size_t)(b * S_ + j0 + sr)) * D_ + h * DH_ + sc0;
            *(bf16x8*)&k_s[sr][sc0] = *(const bf16x8*)kp;
            const short* vp = vbfT + ((size_t)(b * H_ + h) * DH_ + sr) * S_ + j0 + sc0;
            *(bf16x8*)&vT_s[sr][sc0] = *(const bf16x8*)vp;
        } else {
            short kv[8];
            if (sr < KT_) {
                const float* rp = ret + ((size_t)(b * KT_ + sr)) * D_ + h * DH_ + sc0;
                float4 a0 = *(const float4*)rp;
                float4 a1 = *(const float4*)(rp + 4);
                kv[0] = (short)f2bf(a0.x); kv[1] = (short)f2bf(a0.y);
                kv[2] = (short)f2bf(a0.z); kv[3] = (short)f2bf(a0.w);
                kv[4] = (short)f2bf(a1.x); kv[5] = (short)f2bf(a1.y);
                kv[6] = (short)f2bf(a1.z); kv[7] = (short)f2bf(a1.w);
            } else {
#pragma unroll
                for (int i = 0; i < 8; ++i) kv[i] = 0;
            }
            *(bf16x8*)&k_s[sr][sc0] = *(bf16x8*)&kv[0];
        }
        __syncthreads();   // k_s (and vT_s if real tile) ready
        if (memtile) {
            // vT_s[d][key] = k_s[key][d] via in-LDS transpose (identical bits)
            short tv[8];
#pragma unroll
            for (int i = 0; i < 8; ++i) {
                int key = sc0 + i;
                tv[i] = (key < KT_) ? k_s[key][sr] : (short)0;
            }
            *(bf16x8*)&vT_s[sr][sc0] = *(bf16x8*)&tv[0];
            // visible to PV by the p_s __syncthreads below
        }

        // ---- QK^T scores (C: row = lg*4+reg = query, col = lc = key) ----
        float sc[4][4];
        int am[4];
        if (!memtile) {
#pragma unroll
            for (int kt = 0; kt < 4; ++kt) am[kt] = amask[b * S_ + j0 + kt * 16 + lc];
        }
#pragma unroll
        for (int kt = 0; kt < 4; ++kt) {
            f32x4 s = {0.0f, 0.0f, 0.0f, 0.0f};
            if (!memtile || kt == 0) {
                bf16x8 k0 = *(const bf16x8*)&k_s[kt * 16 + lc][lg * 8];
                bf16x8 k1 = *(const bf16x8*)&k_s[kt * 16 + lc][32 + lg * 8];
                s = __builtin_amdgcn_mfma_f32_16x16x32_bf16(qfr[0], k0, s, 0, 0, 0);
                s = __builtin_amdgcn_mfma_f32_16x16x32_bf16(qfr[1], k1, s, 0, 0, 0);
            }
#pragma unroll
            for (int reg = 0; reg < 4; ++reg) {
                int qi = qb + lg * 4 + reg;
                if (memtile) {
                    sc[kt][reg] = (kt == 0 && lc < KT_) ? s[reg] * 0.125f : -INFINITY;
                } else {
                    int jg = j0 + kt * 16 + lc;
                    bool vis = (jg <= qi) && (am[kt] > 0);
                    sc[kt][reg] = vis ? (s[reg] * 0.125f - slope * (float)(qi - jg)) : -INFINITY;
                }
            }
        }

        // ---- online softmax (register-resident, 16-lane shuffle reduce) ----
        float pv_[4][4];
#pragma unroll
        for (int reg = 0; reg < 4; ++reg) {
            float tm = fmaxf(fmaxf(sc[0][reg], sc[1][reg]), fmaxf(sc[2][reg], sc[3][reg]));
#pragma unroll
            for (int msk = 1; msk <= 8; msk <<= 1) tm = fmaxf(tm, __shfl_xor(tm, msk));
            float mnew = fmaxf(mrow[reg], tm);
            fac[reg] = __expf(mrow[reg] - mnew);
            mrow[reg] = mnew;
            float rs = 0.0f;
#pragma unroll
            for (int kt = 0; kt < 4; ++kt) {
                float p = __expf(sc[kt][reg] - mnew);
                pv_[kt][reg] = p;
                rs += p;
            }
#pragma unroll
            for (int msk = 1; msk <= 8; msk <<= 1) rs += __shfl_xor(rs, msk);
            lrow[reg] = lrow[reg] * fac[reg] + rs;
        }

        // ---- write P to per-wave LDS as bf16 pairs ----
        int parity = l & 1;
        int ktw = memtile ? 2 : 4;
        for (int kt = 0; kt < ktw; ++kt) {
#pragma unroll
            for (int rp = 0; rp < 4; rp += 2) {
                float s0 = (memtile && kt == 1) ? 0.0f : pv_[kt][rp];
                float s1 = (memtile && kt == 1) ? 0.0f : pv_[kt][rp + 1];
                float o0 = __shfl_xor(s0, 1);
                float o1 = __shfl_xor(s1, 1);
                float lo, hi; int reg;
                if (parity == 0) { lo = s0; hi = o0; reg = rp; }
                else             { lo = o1; hi = s1; reg = rp + 1; }
                unsigned pk = (unsigned)f2bf(lo) | ((unsigned)f2bf(hi) << 16);
                *(unsigned*)&p_s[w][lg * 4 + reg][kt * 16 + (lc & ~1)] = pk;
            }
        }
        __syncthreads();   // p_s + (memtile vT_s) ready

        // ---- PV accumulate ----
#pragma unroll
        for (int db = 0; db < 4; ++db) {
#pragma unroll
            for (int reg = 0; reg < 4; ++reg) O[db][reg] *= fac[reg];
        }
        int nkh = memtile ? 1 : 2;
        for (int kh = 0; kh < nkh; ++kh) {
            bf16x8 a = *(const bf16x8*)&p_s[w][lc][kh * 32 + lg * 8];
#pragma unroll
            for (int db = 0; db < 4; ++db) {
                bf16x8 vb = *(const bf16x8*)&vT_s[db * 16 + lc][kh * 32 + lg * 8];
                O[db] = __builtin_amdgcn_mfma_f32_16x16x32_bf16(a, vb, O[db], 0, 0, 0);
            }
        }
    }

    // ---- epilogue: write bf16 h/m splits of attention output ----
#pragma unroll
    for (int db = 0; db < 4; ++db) {
#pragma unroll
        for (int reg = 0; reg < 4; ++reg) {
            int qi = qb + lg * 4 + reg;
            size_t idx2 = ((size_t)(b * S_ + qi)) * D_ + h * DH_ + db * 16 + lc;
            float o = O[db][reg] / lrow[reg];
            unsigned short hb2 = f2bf(o);
            float hf = bf2f(hb2);
            unsigned short mb = f2bf(o - hf);
            AOh[idx2] = (short)hb2;
            AOm[idx2] = (short)mb;
        }
    }
}

// ---------------- launch ----------------
extern "C" void kernel_launch(void* const* d_in, const int* in_sizes, int n_in,
                              void* d_out, int out_size, void* d_ws, size_t ws_size,
                              hipStream_t stream)
{
    const float* X = (const float*)d_in[0];
    const int* amask = (const int*)d_in[1];
    const float* Wq = (const float*)d_in[2];
    const float* Wk = (const float*)d_in[3];
    const float* Wv = (const float*)d_in[4];
    const float* Wo = (const float*)d_in[5];
    float* out = (float*)d_out;

    char* p = (char*)d_ws;
    auto alloc = [&](size_t bytes) -> char* {
        char* r = p; p += (bytes + 255) & ~(size_t)255; return r;
    };
    double* sur = (double*)alloc((size_t)B_ * S_ * sizeof(double));
    float* kacc = (float*)alloc((size_t)2 * BS_ * D_ * sizeof(float));  // kf | kp1; reused by O split-K
    float* events = (float*)alloc((size_t)EVCAP_ * D_ * sizeof(float));
    float* ret = (float*)alloc((size_t)B_ * KT_ * D_ * sizeof(float));
    float* sims = (float*)alloc(MEM_ * sizeof(float));
    int* seg_start = (int*)alloc(S_ * sizeof(int));
    int* seg_end = (int*)alloc(S_ * sizeof(int));
    int* scal = (int*)alloc(64);
    short* qbf = (short*)alloc((size_t)BS_ * D_ * sizeof(short));
    short* vbf = (short*)alloc((size_t)BS_ * D_ * sizeof(short));
    short* vbfT = (short*)alloc((size_t)B_ * H_ * DH_ * S_ * sizeof(short));
    short* Xh = (short*)alloc((size_t)BS_ * D_ * sizeof(short));   // reused as AOh
    short* Xm = (short*)alloc((size_t)BS_ * D_ * sizeof(short));   // reused as AOm
    short* Xl = (short*)alloc((size_t)BS_ * D_ * sizeof(short));   // reused as kbf
    short* Wqh = (short*)alloc((size_t)D_ * D_ * sizeof(short));
    short* Wqm = (short*)alloc((size_t)D_ * D_ * sizeof(short));
    short* Wvh = (short*)alloc((size_t)D_ * D_ * sizeof(short));
    short* Wvm = (short*)alloc((size_t)D_ * D_ * sizeof(short));
    short* Woh = (short*)alloc((size_t)D_ * D_ * sizeof(short));
    short* Wom = (short*)alloc((size_t)D_ * D_ * sizeof(short));
    short* Wkh = (short*)alloc((size_t)D_ * D_ * sizeof(short));
    short* Wkm = (short*)alloc((size_t)D_ * D_ * sizeof(short));
    short* Wkl = (short*)alloc((size_t)D_ * D_ * sizeof(short));
    if ((size_t)(p - (char*)d_ws) > ws_size) return;  // insufficient workspace

    float* kf = kacc;
    float* kp1 = kacc + (size_t)BS_ * D_;
    short* kbf = Xl;

    init_counters<<<1, 1, 0, stream>>>(scal);

    int nx4 = BS_ * D_ / 4;
    int nw4 = D_ * D_ / 4;
    split_x_kernel<<<(nx4 + 255) / 256, 256, 0, stream>>>(X, Xh, Xm, Xl, nx4);
    {
        SArgs sa = {};
        sa.src[0] = Wq; sa.h[0] = Wqh; sa.m[0] = Wqm; sa.l[0] = nullptr;
        sa.src[1] = Wk; sa.h[1] = Wkh; sa.m[1] = Wkm; sa.l[1] = Wkl;
        sa.src[2] = Wv; sa.h[2] = Wvh; sa.m[2] = Wvm; sa.l[2] = nullptr;
        sa.src[3] = Wo; sa.h[3] = Woh; sa.m[3] = Wom; sa.l[3] = nullptr;
        split_w_kernel<<<dim3(nw4 / 256, 4), 256, 0, stream>>>(sa);
    }

    // Fused QV + K(split-K 2) GEMM: 4 groups x 8 col-panels x 32 row-panels = 1024 blocks.
    {
        FArgs fa = {};
        fa.A[0][0] = Xm;  fa.A[0][1] = Xh;  fa.A[0][2] = Xh;
        fa.B[0][0] = Wqh; fa.B[0][1] = Wqm; fa.B[0][2] = Wqh;
        fa.outb[0] = qbf;
        fa.A[1][0] = Xm;  fa.A[1][1] = Xh;  fa.A[1][2] = Xh;
        fa.B[1][0] = Wvh; fa.B[1][1] = Wvm; fa.B[1][2] = Wvh;
        fa.outb[1] = vbf;
        fa.A[2][0] = Xh;  fa.A[2][1] = Xm;  fa.A[2][2] = Xm;
        fa.B[2][0] = Wkm; fa.B[2][1] = Wkh; fa.B[2][2] = Wkm;
        fa.outf[2] = kf;
        fa.A[3][0] = Xh;  fa.A[3][1] = Xl;  fa.A[3][2] = Xh;
        fa.B[3][0] = Wkl; fa.B[3][1] = Wkh; fa.B[3][2] = Wkh;
        fa.outf[3] = kp1;
        fa.gsbase[0] = 0; fa.gsbase[1] = 0; fa.gsbase[2] = 0; fa.gsbase[3] = 0;
        fa.nsteps = 48;
        fa.jshift = 5;
        gemm_ms<<<1024, 256, 0, stream>>>(fa);
    }
    transpose_v<<<dim3(S_ / 64, H_, B_), 256, 0, stream>>>(vbf, vbfT);
    addk_kernel<<<BS_ * D_ / 4 / 256, 256, 0, stream>>>(kf, kp1, kbf);

    surprise_kernel<<<dim3(S_, B_), 256, 0, stream>>>(kf, sur);
    for (int b = 0; b < B_; ++b) {
        const float* kfb = kf + (size_t)b * S_ * D_;
        boundary_kernel<<<1, 256, 0, stream>>>(sur + (size_t)b * S_, seg_start, seg_end, scal);
        seg_means_kernel<<<S_, 256, 0, stream>>>(kfb, events, seg_start, seg_end, scal);
        sims_kernel<<<MEM_, 256, 0, stream>>>(events, kfb + (size_t)(S_ - 1) * D_, sims, scal);
        topk_kernel<<<1, 256, 0, stream>>>(events, sims, ret + (size_t)b * KT_ * D_, scal);
    }

    attn_mfma_kernel<<<512, 512, 0, stream>>>(qbf, kbf, vbfT, ret, amask, Xh, Xm);

    // O GEMM: A = attention-output splits (AOm,AOh,AOh), split-K=2, 512 blocks
    {
        FArgs fa = {};
        fa.A[0][0] = Xm;  fa.A[0][1] = Xh;  fa.A[0][2] = Xh;
        fa.B[0][0] = Woh; fa.B[0][1] = Wom; fa.B[0][2] = Woh;
        fa.outf[0] = kf;
        fa.A[1][0] = Xm;  fa.A[1][1] = Xh;  fa.A[1][2] = Xh;
        fa.B[1][0] = Woh; fa.B[1][1] = Wom; fa.B[1][2] = Woh;
        fa.outf[1] = kp1;
        fa.gsbase[0] = 0; fa.gsbase[1] = 24;
        fa.nsteps = 24;
        fa.jshift = 4;
        gemm_ms<<<512, 256, 0, stream>>>(fa);
    }
    addo_kernel<<<BS_ * D_ / 4 / 256, 256, 0, stream>>>(kf, kp1, out);
}